// Round 5
// baseline (584.699 us; speedup 1.0000x reference)
//
#include <hip/hip_runtime.h>
#include <hip/hip_bf16.h>
#include <stdint.h>

typedef unsigned short u16;
typedef __attribute__((ext_vector_type(8))) short short8;
typedef __attribute__((ext_vector_type(8))) __bf16 bf16x8;
typedef __attribute__((ext_vector_type(4))) float f32x4;
typedef __attribute__((ext_vector_type(4))) float fv4;

#define DEV static __device__ __forceinline__

DEV float bf2f(u16 u) { uint32_t i = ((uint32_t)u) << 16; float f; __builtin_memcpy(&f, &i, 4); return f; }
DEV u16 f2bf(float f) {
    uint32_t i; __builtin_memcpy(&i, &f, 4);
    uint32_t r = i + 0x7FFFu + ((i >> 16) & 1u);
    return (u16)(r >> 16);
}
DEV float lo16f(uint32_t u) { uint32_t i = u << 16; float f; __builtin_memcpy(&f, &i, 4); return f; }
DEV float hi16f(uint32_t u) { uint32_t i = u & 0xFFFF0000u; float f; __builtin_memcpy(&f, &i, 4); return f; }
DEV uint32_t pack2(float a, float b) { return (uint32_t)f2bf(a) | ((uint32_t)f2bf(b) << 16); }
DEV float lrelu(float x) { return x >= 0.f ? x : 0.2f * x; }

#define CHK 4096      // edges per partition block
#define BN2SH 10      // 1024 nodes per bucket
#define BN2 1024

// ---------------- CSR build: atomic-free bucket partition ----------------
// pass 1: per-block histogram of dst buckets
__global__ __launch_bounds__(256) void k_hist(const int* __restrict__ dst, int* __restrict__ hist,
                                              int NBUK, int nbp, int E) {
    __shared__ int h[BN2];
    int tid = threadIdx.x;
    for (int i = tid; i < NBUK; i += 256) h[i] = 0;
    __syncthreads();
    int b0 = blockIdx.x * CHK;
    int jend = b0 + CHK < E ? b0 + CHK : E;
    for (int j = b0 + tid; j < jend; j += 256)
        atomicAdd(&h[dst[j] >> BN2SH], 1);
    __syncthreads();
    for (int i = tid; i < NBUK; i += 256) hist[i * nbp + blockIdx.x] = h[i];
}

__global__ void k_scanpart(const int* __restrict__ deg, int* __restrict__ bsum, int n) {
    __shared__ int buf[1024];
    int tid = threadIdx.x;
    int i = blockIdx.x * 1024 + tid;
    int v = (i < n) ? deg[i] : 0;
    buf[tid] = v; __syncthreads();
    for (int d = 512; d > 0; d >>= 1) {
        if (tid < d) buf[tid] += buf[tid + d];
        __syncthreads();
    }
    if (tid == 0) bsum[blockIdx.x] = buf[0];
}

__global__ void k_scanbsum(int* bsum, int nb) {
    if (threadIdx.x == 0) {
        int run = 0;
        for (int b = 0; b < nb; ++b) { int t = bsum[b]; bsum[b] = run; run += t; }
    }
}

__global__ void k_scanonly(const int* __restrict__ in, const int* __restrict__ bsum,
                           int* __restrict__ out, int n) {
    __shared__ int buf[1024];
    int tid = threadIdx.x;
    int i = blockIdx.x * 1024 + tid;
    int v = (i < n) ? in[i] : 0;
    buf[tid] = v; __syncthreads();
    for (int d = 1; d < 1024; d <<= 1) {
        int t = (tid >= d) ? buf[tid - d] : 0;
        __syncthreads();
        buf[tid] += t;
        __syncthreads();
    }
    if (i < n) out[i] = buf[tid] - v + bsum[blockIdx.x];
}

// pass 3: partition edges into bucket-contiguous staging via LDS cursors
// stage entry packed: src (17 bits) | local_dst (10 bits) << 17   [N=100000 < 2^17]
__global__ __launch_bounds__(256) void k_part(const int* __restrict__ src, const int* __restrict__ dst,
                                              const int* __restrict__ scanned, int* __restrict__ stage,
                                              int NBUK, int nbp, int E) {
    __shared__ int cur[BN2];
    int tid = threadIdx.x;
    for (int i = tid; i < NBUK; i += 256) cur[i] = scanned[i * nbp + blockIdx.x];
    __syncthreads();
    int b0 = blockIdx.x * CHK;
    int jend = b0 + CHK < E ? b0 + CHK : E;
    for (int j = b0 + tid; j < jend; j += 256) {
        int d = dst[j];
        int p = atomicAdd(&cur[d >> BN2SH], 1);
        stage[p] = src[j] | ((d & (BN2 - 1)) << 17);
    }
}

// level 2: exact CSR within each bucket (LDS-only atomics, coalesced/local writes)
__global__ __launch_bounds__(256) void k_csr(const int* __restrict__ stage, const int* __restrict__ scanned,
                                             int* __restrict__ off, int* __restrict__ srt,
                                             int NBUK, int nbp, int N, int E) {
    __shared__ int deg[BN2];
    __shared__ int ex[BN2];
    __shared__ int tsum[256];
    int tid = threadIdx.x, b = blockIdx.x;
    int base = b << BN2SH;
    int s0 = scanned[b * nbp];
    int s1 = (b + 1 < NBUK) ? scanned[(b + 1) * nbp] : E;
    for (int i = tid; i < BN2; i += 256) deg[i] = 0;
    __syncthreads();
    for (int j = s0 + tid; j < s1; j += 256) atomicAdd(&deg[(uint32_t)stage[j] >> 17], 1);
    __syncthreads();
    int t4 = tid * 4;
    int d0 = deg[t4], d1 = deg[t4 + 1], d2 = deg[t4 + 2], d3 = deg[t4 + 3];
    int tot = d0 + d1 + d2 + d3;
    tsum[tid] = tot; __syncthreads();
    for (int d = 1; d < 256; d <<= 1) {
        int t = (tid >= d) ? tsum[tid - d] : 0;
        __syncthreads();
        tsum[tid] += t;
        __syncthreads();
    }
    int ebase = tsum[tid] - tot;
    ex[t4] = ebase; ex[t4 + 1] = ebase + d0; ex[t4 + 2] = ebase + d0 + d1; ex[t4 + 3] = ebase + d0 + d1 + d2;
    __syncthreads();
    for (int i = tid; i < BN2; i += 256) { int n = base + i; if (n < N) off[n] = s0 + ex[i]; }
    if (b == 0 && tid == 0) off[N] = E;
    __syncthreads();
    for (int j = s0 + tid; j < s1; j += 256) {
        int sd = stage[j];
        int p = atomicAdd(&ex[(uint32_t)sd >> 17], 1);
        srt[s0 + p] = sd & 0x1FFFF;
    }
}

// ---------------- GEMM: out[N,M](bf16) = concat(A1[N,K1],A2[N,K2])(bf16) @ W[K,M](f32) ----------------
// If A1f != nullptr (layer 1): stage A from f32 source, convert in-register, and also
// emit the bf16 copy to xbout (side-output; replaces the separate k_cvt pass).
__global__ __launch_bounds__(256) void gemm_k(const u16* __restrict__ A1, int K1,
                                              const u16* __restrict__ A2, int K2,
                                              const float* __restrict__ W, int M,
                                              u16* __restrict__ out, int N,
                                              const float* __restrict__ A1f,
                                              u16* __restrict__ xbout) {
    __shared__ u16 wt[64][328];
    __shared__ u16 As[64][40];
    const int K = K1 + K2;
    const int tid = threadIdx.x;
    const int n0 = blockIdx.x * 64;
    const int cb = blockIdx.y * 64;

    for (int idx = tid; idx < K * 64; idx += 256) {
        int k = idx >> 6, m = idx & 63;
        wt[m][k] = f2bf(W[(size_t)k * M + cb + m]);
    }

    const int wv = tid >> 6, lane = tid & 63;
    const int quad = lane >> 4, r = lane & 15;
    f32x4 acc[4];
#pragma unroll
    for (int ct = 0; ct < 4; ++ct) acc[ct] = (f32x4){0.f, 0.f, 0.f, 0.f};

    const int row = tid >> 2, seg = tid & 3;
    const int gl = n0 + row;

    for (int k0 = 0; k0 < K; k0 += 32) {
        int4 v = {0, 0, 0, 0};
        if (gl < N) {
            if (A1f) {
                const float* fb = A1f + (size_t)gl * K + k0 + seg * 8;
                fv4 f0 = *(const fv4*)fb;
                fv4 f1 = *(const fv4*)(fb + 4);
                v.x = (int)pack2(f0.x, f0.y); v.y = (int)pack2(f0.z, f0.w);
                v.z = (int)pack2(f1.x, f1.y); v.w = (int)pack2(f1.z, f1.w);
                if (cb == 0) *(int4*)(xbout + (size_t)gl * K + k0 + seg * 8) = v;
            } else {
                const u16* base = (k0 < K1) ? (A1 + (size_t)gl * K1 + k0)
                                            : (A2 + (size_t)gl * K2 + (k0 - K1));
                v = *(const int4*)(base + seg * 8);
            }
        }
        *(int4*)&As[row][seg * 8] = v;
        __syncthreads();
        bf16x8 a = __builtin_bit_cast(bf16x8, *(const short8*)&As[wv * 16 + r][quad * 8]);
#pragma unroll
        for (int ct = 0; ct < 4; ++ct) {
            bf16x8 b = __builtin_bit_cast(bf16x8, *(const short8*)&wt[ct * 16 + r][k0 + quad * 8]);
            acc[ct] = __builtin_amdgcn_mfma_f32_16x16x32_bf16(a, b, acc[ct], 0, 0, 0);
        }
        __syncthreads();
    }

#pragma unroll
    for (int ct = 0; ct < 4; ++ct)
#pragma unroll
        for (int rg = 0; rg < 4; ++rg) {
            int grow = n0 + wv * 16 + quad * 4 + rg;
            if (grow < N) out[(size_t)grow * M + cb + ct * 16 + r] = f2bf(acc[ct][rg]);
        }
}

// ---------------- attention coefficients: a_src/a_dst [N,8] fp32 ----------------
__global__ __launch_bounds__(256) void acomp8(const u16* __restrict__ g,
                                              const float* __restrict__ ats, const float* __restrict__ atd,
                                              float* __restrict__ a_src, float* __restrict__ a_dst, int N) {
    int lane = threadIdx.x & 63;
    int node = blockIdx.x * 4 + (threadIdx.x >> 6);
    if (node >= N) return;
    float val = bf2f(g[(size_t)node * 64 + lane]);
    float ps = val * ats[lane];
    float pd = val * atd[lane];
#pragma unroll
    for (int d = 1; d < 8; d <<= 1) { ps += __shfl_xor(ps, d); pd += __shfl_xor(pd, d); }
    if ((lane & 7) == 0) {
        a_src[node * 8 + (lane >> 3)] = ps;
        a_dst[node * 8 + (lane >> 3)] = pd;
    }
}

__global__ __launch_bounds__(256) void acomp16(const u16* __restrict__ g,
                                               const float* __restrict__ ats, const float* __restrict__ atd,
                                               float* __restrict__ a_src, float* __restrict__ a_dst, int N) {
    int lane = threadIdx.x & 63;
    int node = blockIdx.x * 4 + (threadIdx.x >> 6);
    if (node >= N) return;
    float v0 = bf2f(g[(size_t)node * 128 + lane]);
    float v1 = bf2f(g[(size_t)node * 128 + lane + 64]);
    float ps0 = v0 * ats[lane],      pd0 = v0 * atd[lane];
    float ps1 = v1 * ats[lane + 64], pd1 = v1 * atd[lane + 64];
#pragma unroll
    for (int d = 1; d < 16; d <<= 1) {
        ps0 += __shfl_xor(ps0, d); pd0 += __shfl_xor(pd0, d);
        ps1 += __shfl_xor(ps1, d); pd1 += __shfl_xor(pd1, d);
    }
    if ((lane & 15) == 0) {
        int hd = lane >> 4;
        a_src[node * 8 + hd] = ps0;     a_dst[node * 8 + hd] = pd0;
        a_src[node * 8 + hd + 4] = ps1; a_dst[node * 8 + hd + 4] = pd1;
    }
}

// ---------------- layer 1/2 aggregation: 2 nodes/wave, 4 channels/lane (dwordx2 gather) ----------------
// Per half-wave (one node): gather layout lane16 = ch-group (4 ch), sub = edge sub-slot (2 edges/gather).
// Weight layout (per half-wave): hw = lane&7 (head), e4 = edge slot (4 edges/outer-iter).
// Tail masking via pre-zeroed weights at the source lane (no per-t cndmask).
__global__ __launch_bounds__(256) void agg12(const u16* __restrict__ g,
                                             const float* __restrict__ a_src, const float* __restrict__ a_dst,
                                             const int* __restrict__ off, const int* __restrict__ srt,
                                             const float* __restrict__ bias, const float* __restrict__ pslope,
                                             u16* __restrict__ hout, int N) {
    int tid = threadIdx.x;
    int lane32 = tid & 31;
    int node = blockIdx.x * 8 + (tid >> 5);
    int nd = node < N ? node : N - 1;
    int lane16 = lane32 & 15;     // channel group: ch [lane16*4, +4)
    int sub    = lane32 >> 4;     // edge sub-slot (0..1)
    int hg     = lane16 >> 1;     // head of gather channels (8 ch/head)
    int hw     = lane32 & 7;      // head for weight layout
    int e4     = lane32 >> 3;     // edge slot for weight layout (0..3)
    const char* gb = (const char*)g;

    float ad_acc = a_dst[nd * 8 + hg];
    float ad_w   = a_dst[nd * 8 + hw];
    float ws = __expf(lrelu(a_src[nd * 8 + hg] + ad_acc));
    float m0 = (sub == 0) ? ws : 0.f;        // self-loop counted once
    uint2 gs = *(const uint2*)(gb + ((size_t)nd << 7) + lane16 * 8);
    float s = m0;
    float acc0 = m0 * lo16f(gs.x), acc1 = m0 * hi16f(gs.x);
    float acc2 = m0 * lo16f(gs.y), acc3 = m0 * hi16f(gs.y);

    int jb = off[nd], je = off[nd + 1];
    int addrH = (tid & 32) * 4;               // byte addr of half-wave base lane
    int addrS = addrH + sub * 32;             // srcv bpermute base (t2 adds +64)
    int addrW = addrS + hg * 4;               // weight bpermute base
    int laneoff = lane16 * 8;                 // byte offset within 128B row

    int idx = 0; float asv = 0.f;
    if (jb < je) {
        int jc = jb + e4; jc = jc < je ? jc : je - 1;
        idx = srt[jc];
        asv = a_src[idx * 8 + hw];
    }
    for (int j = jb; j < je; j += 4) {
        float w = __expf(lrelu(asv + ad_w));
        w = (j + e4 < je) ? w : 0.f;          // pre-zero tail weights at source
        int wi = __builtin_bit_cast(int, w);
        int jn = j + 4 + e4; jn = jn < je ? jn : je - 1;
        int idx_n = srt[jn];
        float as_n = a_src[idx_n * 8 + hw];

        int sv0 = __builtin_amdgcn_ds_bpermute(addrS,      idx);
        int wb0 = __builtin_amdgcn_ds_bpermute(addrW,      wi);
        int sv1 = __builtin_amdgcn_ds_bpermute(addrS + 64, idx);
        int wb1 = __builtin_amdgcn_ds_bpermute(addrW + 64, wi);
        uint2 g0 = *(const uint2*)(gb + (((uint32_t)sv0 << 7) + laneoff));
        uint2 g1 = *(const uint2*)(gb + (((uint32_t)sv1 << 7) + laneoff));
        float wv0 = __builtin_bit_cast(float, wb0);
        float wv1 = __builtin_bit_cast(float, wb1);
        s += wv0;
        acc0 += wv0 * lo16f(g0.x); acc1 += wv0 * hi16f(g0.x);
        acc2 += wv0 * lo16f(g0.y); acc3 += wv0 * hi16f(g0.y);
        s += wv1;
        acc0 += wv1 * lo16f(g1.x); acc1 += wv1 * hi16f(g1.x);
        acc2 += wv1 * lo16f(g1.y); acc3 += wv1 * hi16f(g1.y);
        idx = idx_n; asv = as_n;
    }
    // combine the two edge sub-slots (lanes ^16, within each half-wave)
    s    += __shfl_xor(s,    16);
    acc0 += __shfl_xor(acc0, 16); acc1 += __shfl_xor(acc1, 16);
    acc2 += __shfl_xor(acc2, 16); acc3 += __shfl_xor(acc3, 16);
    if (node < N && sub == 0) {
        float r = 1.f / (s + 1e-16f);
        fv4 bv = *(const fv4*)(bias + lane16 * 4);
        float p = pslope[0];
        float v0 = acc0 * r + bv.x; v0 = v0 >= 0.f ? v0 : p * v0;
        float v1 = acc1 * r + bv.y; v1 = v1 >= 0.f ? v1 : p * v1;
        float v2 = acc2 * r + bv.z; v2 = v2 >= 0.f ? v2 : p * v2;
        float v3 = acc3 * r + bv.w; v3 = v3 >= 0.f ? v3 : p * v3;
        uint2 o; o.x = pack2(v0, v1); o.y = pack2(v2, v3);
        *(uint2*)((char*)hout + ((size_t)node << 7) + lane16 * 8) = o;
    }
}

// ---------------- layer 3 aggregation + head-mean + bias + log_softmax ----------------
// 1 node/wave. Gather layout: lane32 = ch-group (4 ch of 128), sub = lane>>5 (2 edges/gather).
// Weight layout: hw = lane&7 (head), e8 = lane>>3 (8 edges/outer-iter).
__global__ __launch_bounds__(256) void agg3(const u16* __restrict__ g,
                                            const float* __restrict__ a_src, const float* __restrict__ a_dst,
                                            const int* __restrict__ off, const int* __restrict__ srt,
                                            const float* __restrict__ b3, float* __restrict__ out, int N) {
    int tid = threadIdx.x;
    int lane = tid & 63;
    int node = blockIdx.x * 4 + (tid >> 6);
    int nd = node < N ? node : N - 1;
    int lane32 = lane & 31;       // ch group: ch [lane32*4, +4)
    int sub = lane >> 5;          // edge sub-slot (0..1)
    int hg = lane32 >> 2;         // head of gather channels (16 ch/head)
    int hw = lane & 7;            // head for weight layout
    int e8 = lane >> 3;           // edge slot for weight layout (0..7)
    const char* gb = (const char*)g;

    float ad_acc = a_dst[nd * 8 + hg];
    float ad_w   = a_dst[nd * 8 + hw];
    float ws = __expf(lrelu(a_src[nd * 8 + hg] + ad_acc));
    float m0 = (sub == 0) ? ws : 0.f;
    uint2 gs = *(const uint2*)(gb + ((size_t)nd << 8) + lane32 * 8);
    float s = m0;
    float acc0 = m0 * lo16f(gs.x), acc1 = m0 * hi16f(gs.x);
    float acc2 = m0 * lo16f(gs.y), acc3 = m0 * hi16f(gs.y);

    int jb = off[nd], je = off[nd + 1];
    int addrS = sub * 32;                 // srcv bpermute base (t adds +64)
    int addrW = addrS + hg * 4;           // weight bpermute base
    int laneoff = lane32 * 8;             // byte offset within 256B row

    int idx = 0; float asv = 0.f;
    if (jb < je) {
        int jc = jb + e8; jc = jc < je ? jc : je - 1;
        idx = srt[jc];
        asv = a_src[idx * 8 + hw];
    }
    for (int j = jb; j < je; j += 8) {
        float w = __expf(lrelu(asv + ad_w));
        w = (j + e8 < je) ? w : 0.f;      // pre-zero tail weights
        int wi = __builtin_bit_cast(int, w);
        int jn = j + 8 + e8; jn = jn < je ? jn : je - 1;
        int idx_n = srt[jn];
        float as_n = a_src[idx_n * 8 + hw];
#pragma unroll
        for (int t = 0; t < 4; ++t) {
            int sv = __builtin_amdgcn_ds_bpermute(addrS + t * 64, idx);
            int wb = __builtin_amdgcn_ds_bpermute(addrW + t * 64, wi);
            uint2 gv = *(const uint2*)(gb + (((uint32_t)sv << 8) + laneoff));
            float wf = __builtin_bit_cast(float, wb);
            s += wf;
            acc0 += wf * lo16f(gv.x); acc1 += wf * hi16f(gv.x);
            acc2 += wf * lo16f(gv.y); acc3 += wf * hi16f(gv.y);
        }
        idx = idx_n; asv = as_n;
    }
    // combine edge sub-slots (lanes ^32)
    s    += __shfl_xor(s,    32);
    acc0 += __shfl_xor(acc0, 32); acc1 += __shfl_xor(acc1, 32);
    acc2 += __shfl_xor(acc2, 32); acc3 += __shfl_xor(acc3, 32);
    // per-head normalize
    float r = 1.f / (s + 1e-16f);
    acc0 *= r; acc1 *= r; acc2 *= r; acc3 *= r;
    // mean over heads: sum lanes stride-4 (xor 4,8,16)
#pragma unroll
    for (int d = 4; d <= 16; d <<= 1) {
        acc0 += __shfl_xor(acc0, d); acc1 += __shfl_xor(acc1, d);
        acc2 += __shfl_xor(acc2, d); acc3 += __shfl_xor(acc3, d);
    }
    // each lane now holds out-ch [(lane32&3)*4, +4) of the 16 outputs
    fv4 bv = *(const fv4*)(b3 + (lane32 & 3) * 4);
    float v0 = acc0 * 0.125f + bv.x;
    float v1 = acc1 * 0.125f + bv.y;
    float v2 = acc2 * 0.125f + bv.z;
    float v3 = acc3 * 0.125f + bv.w;
    float m = fmaxf(fmaxf(v0, v1), fmaxf(v2, v3));
    m = fmaxf(m, __shfl_xor(m, 1)); m = fmaxf(m, __shfl_xor(m, 2));
    float se = __expf(v0 - m) + __expf(v1 - m) + __expf(v2 - m) + __expf(v3 - m);
    se += __shfl_xor(se, 1); se += __shfl_xor(se, 2);
    float lg = __logf(se);
    if (node < N && lane < 4) {
        float4 o;
        o.x = v0 - m - lg; o.y = v1 - m - lg; o.z = v2 - m - lg; o.w = v3 - m - lg;
        *(float4*)(out + (size_t)node * 16 + lane * 4) = o;
    }
}

// ---------------- launch ----------------
extern "C" void kernel_launch(void* const* d_in, const int* in_sizes, int n_in,
                              void* d_out, int out_size, void* d_ws, size_t ws_size,
                              hipStream_t stream) {
    (void)n_in; (void)out_size; (void)ws_size;
    const float* x  = (const float*)d_in[0];
    const int* ei   = (const int*)d_in[1];
    const float* W1 = (const float*)d_in[2];
    const float* as1 = (const float*)d_in[3];
    const float* ad1 = (const float*)d_in[4];
    const float* b1  = (const float*)d_in[5];
    const float* W2  = (const float*)d_in[6];
    const float* as2 = (const float*)d_in[7];
    const float* ad2 = (const float*)d_in[8];
    const float* b2  = (const float*)d_in[9];
    const float* W3  = (const float*)d_in[10];
    const float* as3 = (const float*)d_in[11];
    const float* ad3 = (const float*)d_in[12];
    const float* b3  = (const float*)d_in[13];
    const float* p1  = (const float*)d_in[14];
    const float* p2  = (const float*)d_in[15];
    const int N = in_sizes[0] / 256;
    const int E = in_sizes[1] / 2;
    const int NBUK = (N + BN2 - 1) >> BN2SH;
    const int nbp = (E + CHK - 1) / CHK;
    const int nsc = NBUK * nbp;

    char* ws = (char*)d_ws;
    size_t o = 0;
    auto alloc = [&](size_t bytes) { void* p = ws + o; o = (o + bytes + 255) & ~(size_t)255; return p; };
    int* off     = (int*)alloc((size_t)(N + 1) * 4);
    int* bsum    = (int*)alloc(4096);
    int* hist    = (int*)alloc((size_t)nsc * 4);
    int* scanned = (int*)alloc((size_t)nsc * 4);
    int* srt     = (int*)alloc((size_t)E * 4);
    int* stage   = (int*)alloc((size_t)E * 4);
    u16* xb      = (u16*)alloc((size_t)N * 256 * 2);
    u16* g       = (u16*)alloc((size_t)N * 128 * 2);
    float* a_src = (float*)alloc((size_t)N * 8 * 4);
    float* a_dst = (float*)alloc((size_t)N * 8 * 4);
    u16* h1      = (u16*)alloc((size_t)N * 64 * 2);
    u16* h2      = (u16*)alloc((size_t)N * 64 * 2);

    // CSR build (atomic-free)
    k_hist<<<nbp, 256, 0, stream>>>(ei + E, hist, NBUK, nbp, E);
    int nS = (nsc + 1023) / 1024;
    k_scanpart<<<nS, 1024, 0, stream>>>(hist, bsum, nsc);
    k_scanbsum<<<1, 64, 0, stream>>>(bsum, nS);
    k_scanonly<<<nS, 1024, 0, stream>>>(hist, bsum, scanned, nsc);
    k_part<<<nbp, 256, 0, stream>>>(ei, ei + E, scanned, stage, NBUK, nbp, E);
    k_csr<<<NBUK, 256, 0, stream>>>(stage, scanned, off, srt, NBUK, nbp, N, E);

    int nb64 = (N + 63) / 64;
    int nb4 = (N + 3) / 4;
    int nb8 = (N + 7) / 8;

    // layer 1: x[N,256] @ W1[256,64]  (A staged from f32, xb emitted as side-output)
    gemm_k<<<dim3(nb64, 1), 256, 0, stream>>>(xb, 256, (const u16*)nullptr, 0, W1, 64, g, N, x, xb);
    acomp8<<<nb4, 256, 0, stream>>>(g, as1, ad1, a_src, a_dst, N);
    agg12<<<nb8, 256, 0, stream>>>(g, a_src, a_dst, off, srt, b1, p1, h1, N);

    // layer 2: concat(x, h1)[N,320] @ W2[320,64]
    gemm_k<<<dim3(nb64, 1), 256, 0, stream>>>(xb, 256, h1, 64, W2, 64, g, N, nullptr, nullptr);
    acomp8<<<nb4, 256, 0, stream>>>(g, as2, ad2, a_src, a_dst, N);
    agg12<<<nb8, 256, 0, stream>>>(g, a_src, a_dst, off, srt, b2, p2, h2, N);

    // layer 3: h2[N,64] @ W3[64,128], mean over heads + log_softmax
    gemm_k<<<dim3(nb64, 2), 256, 0, stream>>>(h2, 64, (const u16*)nullptr, 0, W3, 128, g, N, nullptr, nullptr);
    acomp16<<<nb4, 256, 0, stream>>>(g, as3, ad3, a_src, a_dst, N);
    agg3<<<nb4, 256, 0, stream>>>(g, a_src, a_dst, off, srt, b3, (float*)d_out, N);
}

// Round 6
// 577.197 us; speedup vs baseline: 1.0130x; 1.0130x over previous
//
#include <hip/hip_runtime.h>
#include <hip/hip_bf16.h>
#include <stdint.h>

typedef unsigned short u16;
typedef __attribute__((ext_vector_type(8))) short short8;
typedef __attribute__((ext_vector_type(8))) __bf16 bf16x8;
typedef __attribute__((ext_vector_type(4))) float f32x4;
typedef __attribute__((ext_vector_type(4))) float fv4;

#define DEV static __device__ __forceinline__

DEV float bf2f(u16 u) { uint32_t i = ((uint32_t)u) << 16; float f; __builtin_memcpy(&f, &i, 4); return f; }
DEV u16 f2bf(float f) {
    uint32_t i; __builtin_memcpy(&i, &f, 4);
    uint32_t r = i + 0x7FFFu + ((i >> 16) & 1u);
    return (u16)(r >> 16);
}
DEV float lo16f(uint32_t u) { uint32_t i = u << 16; float f; __builtin_memcpy(&f, &i, 4); return f; }
DEV float hi16f(uint32_t u) { uint32_t i = u & 0xFFFF0000u; float f; __builtin_memcpy(&f, &i, 4); return f; }
DEV uint32_t pack2(float a, float b) { return (uint32_t)f2bf(a) | ((uint32_t)f2bf(b) << 16); }
DEV float lrelu(float x) { return x >= 0.f ? x : 0.2f * x; }

#define CHK 4096      // edges per partition block
#define BN2SH 10      // 1024 nodes per bucket
#define BN2 1024

// ---------------- x -> bf16 pre-convert (streaming, near-roofline) ----------------
__global__ __launch_bounds__(256) void k_cvt(const float* __restrict__ in, u16* __restrict__ out, int n4) {
    int i = blockIdx.x * 256 + threadIdx.x;
    if (i < n4) {
        fv4 v = __builtin_nontemporal_load((const fv4*)in + i);
        uint64_t o = (uint64_t)f2bf(v.x) | ((uint64_t)f2bf(v.y) << 16)
                   | ((uint64_t)f2bf(v.z) << 32) | ((uint64_t)f2bf(v.w) << 48);
        __builtin_nontemporal_store(o, (uint64_t*)out + i);
    }
}

// ---------------- CSR build: atomic-free bucket partition ----------------
__global__ __launch_bounds__(256) void k_hist(const int* __restrict__ dst, int* __restrict__ hist,
                                              int NBUK, int nbp, int E) {
    __shared__ int h[BN2];
    int tid = threadIdx.x;
    for (int i = tid; i < NBUK; i += 256) h[i] = 0;
    __syncthreads();
    int b0 = blockIdx.x * CHK;
    int jend = b0 + CHK < E ? b0 + CHK : E;
    for (int j = b0 + tid; j < jend; j += 256)
        atomicAdd(&h[dst[j] >> BN2SH], 1);
    __syncthreads();
    for (int i = tid; i < NBUK; i += 256) hist[i * nbp + blockIdx.x] = h[i];
}

__global__ void k_scanpart(const int* __restrict__ deg, int* __restrict__ bsum, int n) {
    __shared__ int buf[1024];
    int tid = threadIdx.x;
    int i = blockIdx.x * 1024 + tid;
    int v = (i < n) ? deg[i] : 0;
    buf[tid] = v; __syncthreads();
    for (int d = 512; d > 0; d >>= 1) {
        if (tid < d) buf[tid] += buf[tid + d];
        __syncthreads();
    }
    if (tid == 0) bsum[blockIdx.x] = buf[0];
}

__global__ void k_scanbsum(int* bsum, int nb) {
    if (threadIdx.x == 0) {
        int run = 0;
        for (int b = 0; b < nb; ++b) { int t = bsum[b]; bsum[b] = run; run += t; }
    }
}

__global__ void k_scanonly(const int* __restrict__ in, const int* __restrict__ bsum,
                           int* __restrict__ out, int n) {
    __shared__ int buf[1024];
    int tid = threadIdx.x;
    int i = blockIdx.x * 1024 + tid;
    int v = (i < n) ? in[i] : 0;
    buf[tid] = v; __syncthreads();
    for (int d = 1; d < 1024; d <<= 1) {
        int t = (tid >= d) ? buf[tid - d] : 0;
        __syncthreads();
        buf[tid] += t;
        __syncthreads();
    }
    if (i < n) out[i] = buf[tid] - v + bsum[blockIdx.x];
}

// pass 3: partition edges into bucket-contiguous staging via LDS cursors
// stage entry packed: src (17 bits) | local_dst (10 bits) << 17   [N=100000 < 2^17]
__global__ __launch_bounds__(256) void k_part(const int* __restrict__ src, const int* __restrict__ dst,
                                              const int* __restrict__ scanned, int* __restrict__ stage,
                                              int NBUK, int nbp, int E) {
    __shared__ int cur[BN2];
    int tid = threadIdx.x;
    for (int i = tid; i < NBUK; i += 256) cur[i] = scanned[i * nbp + blockIdx.x];
    __syncthreads();
    int b0 = blockIdx.x * CHK;
    int jend = b0 + CHK < E ? b0 + CHK : E;
    for (int j = b0 + tid; j < jend; j += 256) {
        int d = dst[j];
        int p = atomicAdd(&cur[d >> BN2SH], 1);
        stage[p] = src[j] | ((d & (BN2 - 1)) << 17);
    }
}

// level 2: exact CSR within each bucket (LDS-only atomics, coalesced/local writes)
__global__ __launch_bounds__(256) void k_csr(const int* __restrict__ stage, const int* __restrict__ scanned,
                                             int* __restrict__ off, int* __restrict__ srt,
                                             int NBUK, int nbp, int N, int E) {
    __shared__ int deg[BN2];
    __shared__ int ex[BN2];
    __shared__ int tsum[256];
    int tid = threadIdx.x, b = blockIdx.x;
    int base = b << BN2SH;
    int s0 = scanned[b * nbp];
    int s1 = (b + 1 < NBUK) ? scanned[(b + 1) * nbp] : E;
    for (int i = tid; i < BN2; i += 256) deg[i] = 0;
    __syncthreads();
    for (int j = s0 + tid; j < s1; j += 256) atomicAdd(&deg[(uint32_t)stage[j] >> 17], 1);
    __syncthreads();
    int t4 = tid * 4;
    int d0 = deg[t4], d1 = deg[t4 + 1], d2 = deg[t4 + 2], d3 = deg[t4 + 3];
    int tot = d0 + d1 + d2 + d3;
    tsum[tid] = tot; __syncthreads();
    for (int d = 1; d < 256; d <<= 1) {
        int t = (tid >= d) ? tsum[tid - d] : 0;
        __syncthreads();
        tsum[tid] += t;
        __syncthreads();
    }
    int ebase = tsum[tid] - tot;
    ex[t4] = ebase; ex[t4 + 1] = ebase + d0; ex[t4 + 2] = ebase + d0 + d1; ex[t4 + 3] = ebase + d0 + d1 + d2;
    __syncthreads();
    for (int i = tid; i < BN2; i += 256) { int n = base + i; if (n < N) off[n] = s0 + ex[i]; }
    if (b == 0 && tid == 0) off[N] = E;
    __syncthreads();
    for (int j = s0 + tid; j < s1; j += 256) {
        int sd = stage[j];
        int p = atomicAdd(&ex[(uint32_t)sd >> 17], 1);
        srt[s0 + p] = sd & 0x1FFFF;
    }
}

// ---------------- GEMM: out[N,M](bf16) = concat(A1[N,K1],A2[N,K2])(bf16) @ W[K,M](f32) ----------------
__global__ __launch_bounds__(256) void gemm_k(const u16* __restrict__ A1, int K1,
                                              const u16* __restrict__ A2, int K2,
                                              const float* __restrict__ W, int M,
                                              u16* __restrict__ out, int N) {
    __shared__ u16 wt[64][328];
    __shared__ u16 As[64][40];
    const int K = K1 + K2;
    const int tid = threadIdx.x;
    const int n0 = blockIdx.x * 64;
    const int cb = blockIdx.y * 64;

    for (int idx = tid; idx < K * 64; idx += 256) {
        int k = idx >> 6, m = idx & 63;
        wt[m][k] = f2bf(W[(size_t)k * M + cb + m]);
    }

    const int wv = tid >> 6, lane = tid & 63;
    const int quad = lane >> 4, r = lane & 15;
    f32x4 acc[4];
#pragma unroll
    for (int ct = 0; ct < 4; ++ct) acc[ct] = (f32x4){0.f, 0.f, 0.f, 0.f};

    const int row = tid >> 2, seg = tid & 3;
    const int gl = n0 + row;

    for (int k0 = 0; k0 < K; k0 += 32) {
        int4 v = {0, 0, 0, 0};
        if (gl < N) {
            const u16* base = (k0 < K1) ? (A1 + (size_t)gl * K1 + k0)
                                        : (A2 + (size_t)gl * K2 + (k0 - K1));
            v = *(const int4*)(base + seg * 8);
        }
        *(int4*)&As[row][seg * 8] = v;
        __syncthreads();
        bf16x8 a = __builtin_bit_cast(bf16x8, *(const short8*)&As[wv * 16 + r][quad * 8]);
#pragma unroll
        for (int ct = 0; ct < 4; ++ct) {
            bf16x8 b = __builtin_bit_cast(bf16x8, *(const short8*)&wt[ct * 16 + r][k0 + quad * 8]);
            acc[ct] = __builtin_amdgcn_mfma_f32_16x16x32_bf16(a, b, acc[ct], 0, 0, 0);
        }
        __syncthreads();
    }

#pragma unroll
    for (int ct = 0; ct < 4; ++ct)
#pragma unroll
        for (int rg = 0; rg < 4; ++rg) {
            int grow = n0 + wv * 16 + quad * 4 + rg;
            if (grow < N) out[(size_t)grow * M + cb + ct * 16 + r] = f2bf(acc[ct][rg]);
        }
}

// ---------------- attention coefficients: a_src/a_dst [N,8] fp32 ----------------
__global__ __launch_bounds__(256) void acomp8(const u16* __restrict__ g,
                                              const float* __restrict__ ats, const float* __restrict__ atd,
                                              float* __restrict__ a_src, float* __restrict__ a_dst, int N) {
    int lane = threadIdx.x & 63;
    int node = blockIdx.x * 4 + (threadIdx.x >> 6);
    if (node >= N) return;
    float val = bf2f(g[(size_t)node * 64 + lane]);
    float ps = val * ats[lane];
    float pd = val * atd[lane];
#pragma unroll
    for (int d = 1; d < 8; d <<= 1) { ps += __shfl_xor(ps, d); pd += __shfl_xor(pd, d); }
    if ((lane & 7) == 0) {
        a_src[node * 8 + (lane >> 3)] = ps;
        a_dst[node * 8 + (lane >> 3)] = pd;
    }
}

__global__ __launch_bounds__(256) void acomp16(const u16* __restrict__ g,
                                               const float* __restrict__ ats, const float* __restrict__ atd,
                                               float* __restrict__ a_src, float* __restrict__ a_dst, int N) {
    int lane = threadIdx.x & 63;
    int node = blockIdx.x * 4 + (threadIdx.x >> 6);
    if (node >= N) return;
    float v0 = bf2f(g[(size_t)node * 128 + lane]);
    float v1 = bf2f(g[(size_t)node * 128 + lane + 64]);
    float ps0 = v0 * ats[lane],      pd0 = v0 * atd[lane];
    float ps1 = v1 * ats[lane + 64], pd1 = v1 * atd[lane + 64];
#pragma unroll
    for (int d = 1; d < 16; d <<= 1) {
        ps0 += __shfl_xor(ps0, d); pd0 += __shfl_xor(pd0, d);
        ps1 += __shfl_xor(ps1, d); pd1 += __shfl_xor(pd1, d);
    }
    if ((lane & 15) == 0) {
        int hd = lane >> 4;
        a_src[node * 8 + hd] = ps0;     a_dst[node * 8 + hd] = pd0;
        a_src[node * 8 + hd + 4] = ps1; a_dst[node * 8 + hd + 4] = pd1;
    }
}

// ---------------- layer 1/2 aggregation: 2 nodes/wave, 4 channels/lane (dwordx2 gather) ----------------
__global__ __launch_bounds__(256) void agg12(const u16* __restrict__ g,
                                             const float* __restrict__ a_src, const float* __restrict__ a_dst,
                                             const int* __restrict__ off, const int* __restrict__ srt,
                                             const float* __restrict__ bias, const float* __restrict__ pslope,
                                             u16* __restrict__ hout, int N) {
    int tid = threadIdx.x;
    int lane32 = tid & 31;
    int node = blockIdx.x * 8 + (tid >> 5);
    int nd = node < N ? node : N - 1;
    int lane16 = lane32 & 15;     // channel group: ch [lane16*4, +4)
    int sub    = lane32 >> 4;     // edge sub-slot (0..1)
    int hg     = lane16 >> 1;     // head of gather channels (8 ch/head)
    int hw     = lane32 & 7;      // head for weight layout
    int e4     = lane32 >> 3;     // edge slot for weight layout (0..3)
    const char* gb = (const char*)g;

    float ad_acc = a_dst[nd * 8 + hg];
    float ad_w   = a_dst[nd * 8 + hw];
    float ws = __expf(lrelu(a_src[nd * 8 + hg] + ad_acc));
    float m0 = (sub == 0) ? ws : 0.f;        // self-loop counted once
    uint2 gs = *(const uint2*)(gb + ((size_t)nd << 7) + lane16 * 8);
    float s = m0;
    float acc0 = m0 * lo16f(gs.x), acc1 = m0 * hi16f(gs.x);
    float acc2 = m0 * lo16f(gs.y), acc3 = m0 * hi16f(gs.y);

    int jb = off[nd], je = off[nd + 1];
    int addrH = (tid & 32) * 4;               // byte addr of half-wave base lane
    int addrS = addrH + sub * 32;             // srcv bpermute base
    int addrW = addrS + hg * 4;               // weight bpermute base
    int laneoff = lane16 * 8;                 // byte offset within 128B row

    int idx = 0; float asv = 0.f;
    if (jb < je) {
        int jc = jb + e4; jc = jc < je ? jc : je - 1;
        idx = srt[jc];
        asv = a_src[idx * 8 + hw];
    }
    for (int j = jb; j < je; j += 4) {
        float w = __expf(lrelu(asv + ad_w));
        w = (j + e4 < je) ? w : 0.f;          // pre-zero tail weights at source
        int wi = __builtin_bit_cast(int, w);
        int jn = j + 4 + e4; jn = jn < je ? jn : je - 1;
        int idx_n = srt[jn];
        float as_n = a_src[idx_n * 8 + hw];

        int sv0 = __builtin_amdgcn_ds_bpermute(addrS,      idx);
        int wb0 = __builtin_amdgcn_ds_bpermute(addrW,      wi);
        int sv1 = __builtin_amdgcn_ds_bpermute(addrS + 64, idx);
        int wb1 = __builtin_amdgcn_ds_bpermute(addrW + 64, wi);
        uint2 g0 = *(const uint2*)(gb + (((uint32_t)sv0 << 7) + laneoff));
        uint2 g1 = *(const uint2*)(gb + (((uint32_t)sv1 << 7) + laneoff));
        float wv0 = __builtin_bit_cast(float, wb0);
        float wv1 = __builtin_bit_cast(float, wb1);
        s += wv0;
        acc0 += wv0 * lo16f(g0.x); acc1 += wv0 * hi16f(g0.x);
        acc2 += wv0 * lo16f(g0.y); acc3 += wv0 * hi16f(g0.y);
        s += wv1;
        acc0 += wv1 * lo16f(g1.x); acc1 += wv1 * hi16f(g1.x);
        acc2 += wv1 * lo16f(g1.y); acc3 += wv1 * hi16f(g1.y);
        idx = idx_n; asv = as_n;
    }
    // combine the two edge sub-slots (lanes ^16, within each half-wave)
    s    += __shfl_xor(s,    16);
    acc0 += __shfl_xor(acc0, 16); acc1 += __shfl_xor(acc1, 16);
    acc2 += __shfl_xor(acc2, 16); acc3 += __shfl_xor(acc3, 16);
    if (node < N && sub == 0) {
        float r = 1.f / (s + 1e-16f);
        fv4 bv = *(const fv4*)(bias + lane16 * 4);
        float p = pslope[0];
        float v0 = acc0 * r + bv.x; v0 = v0 >= 0.f ? v0 : p * v0;
        float v1 = acc1 * r + bv.y; v1 = v1 >= 0.f ? v1 : p * v1;
        float v2 = acc2 * r + bv.z; v2 = v2 >= 0.f ? v2 : p * v2;
        float v3 = acc3 * r + bv.w; v3 = v3 >= 0.f ? v3 : p * v3;
        uint2 o; o.x = pack2(v0, v1); o.y = pack2(v2, v3);
        *(uint2*)((char*)hout + ((size_t)node << 7) + lane16 * 8) = o;
    }
}

// ---------------- layer 3 aggregation + head-mean + bias + log_softmax ----------------
__global__ __launch_bounds__(256) void agg3(const u16* __restrict__ g,
                                            const float* __restrict__ a_src, const float* __restrict__ a_dst,
                                            const int* __restrict__ off, const int* __restrict__ srt,
                                            const float* __restrict__ b3, float* __restrict__ out, int N) {
    int tid = threadIdx.x;
    int lane = tid & 63;
    int node = blockIdx.x * 4 + (tid >> 6);
    int nd = node < N ? node : N - 1;
    int lane32 = lane & 31;       // ch group: ch [lane32*4, +4)
    int sub = lane >> 5;          // edge sub-slot (0..1)
    int hg = lane32 >> 2;         // head of gather channels (16 ch/head)
    int hw = lane & 7;            // head for weight layout
    int e8 = lane >> 3;           // edge slot for weight layout (0..7)
    const char* gb = (const char*)g;

    float ad_acc = a_dst[nd * 8 + hg];
    float ad_w   = a_dst[nd * 8 + hw];
    float ws = __expf(lrelu(a_src[nd * 8 + hg] + ad_acc));
    float m0 = (sub == 0) ? ws : 0.f;
    uint2 gs = *(const uint2*)(gb + ((size_t)nd << 8) + lane32 * 8);
    float s = m0;
    float acc0 = m0 * lo16f(gs.x), acc1 = m0 * hi16f(gs.x);
    float acc2 = m0 * lo16f(gs.y), acc3 = m0 * hi16f(gs.y);

    int jb = off[nd], je = off[nd + 1];
    int addrS = sub * 32;                 // srcv bpermute base (t adds +64)
    int addrW = addrS + hg * 4;           // weight bpermute base
    int laneoff = lane32 * 8;             // byte offset within 256B row

    int idx = 0; float asv = 0.f;
    if (jb < je) {
        int jc = jb + e8; jc = jc < je ? jc : je - 1;
        idx = srt[jc];
        asv = a_src[idx * 8 + hw];
    }
    for (int j = jb; j < je; j += 8) {
        float w = __expf(lrelu(asv + ad_w));
        w = (j + e8 < je) ? w : 0.f;      // pre-zero tail weights
        int wi = __builtin_bit_cast(int, w);
        int jn = j + 8 + e8; jn = jn < je ? jn : je - 1;
        int idx_n = srt[jn];
        float as_n = a_src[idx_n * 8 + hw];
#pragma unroll
        for (int t = 0; t < 4; ++t) {
            int sv = __builtin_amdgcn_ds_bpermute(addrS + t * 64, idx);
            int wb = __builtin_amdgcn_ds_bpermute(addrW + t * 64, wi);
            uint2 gv = *(const uint2*)(gb + (((uint32_t)sv << 8) + laneoff));
            float wf = __builtin_bit_cast(float, wb);
            s += wf;
            acc0 += wf * lo16f(gv.x); acc1 += wf * hi16f(gv.x);
            acc2 += wf * lo16f(gv.y); acc3 += wf * hi16f(gv.y);
        }
        idx = idx_n; asv = as_n;
    }
    // combine edge sub-slots (lanes ^32)
    s    += __shfl_xor(s,    32);
    acc0 += __shfl_xor(acc0, 32); acc1 += __shfl_xor(acc1, 32);
    acc2 += __shfl_xor(acc2, 32); acc3 += __shfl_xor(acc3, 32);
    // per-head normalize
    float r = 1.f / (s + 1e-16f);
    acc0 *= r; acc1 *= r; acc2 *= r; acc3 *= r;
    // mean over heads: sum lanes stride-4 (xor 4,8,16)
#pragma unroll
    for (int d = 4; d <= 16; d <<= 1) {
        acc0 += __shfl_xor(acc0, d); acc1 += __shfl_xor(acc1, d);
        acc2 += __shfl_xor(acc2, d); acc3 += __shfl_xor(acc3, d);
    }
    // each lane now holds out-ch [(lane32&3)*4, +4) of the 16 outputs
    fv4 bv = *(const fv4*)(b3 + (lane32 & 3) * 4);
    float v0 = acc0 * 0.125f + bv.x;
    float v1 = acc1 * 0.125f + bv.y;
    float v2 = acc2 * 0.125f + bv.z;
    float v3 = acc3 * 0.125f + bv.w;
    float m = fmaxf(fmaxf(v0, v1), fmaxf(v2, v3));
    m = fmaxf(m, __shfl_xor(m, 1)); m = fmaxf(m, __shfl_xor(m, 2));
    float se = __expf(v0 - m) + __expf(v1 - m) + __expf(v2 - m) + __expf(v3 - m);
    se += __shfl_xor(se, 1); se += __shfl_xor(se, 2);
    float lg = __logf(se);
    if (node < N && lane < 4) {
        float4 o;
        o.x = v0 - m - lg; o.y = v1 - m - lg; o.z = v2 - m - lg; o.w = v3 - m - lg;
        *(float4*)(out + (size_t)node * 16 + lane * 4) = o;
    }
}

// ---------------- launch ----------------
extern "C" void kernel_launch(void* const* d_in, const int* in_sizes, int n_in,
                              void* d_out, int out_size, void* d_ws, size_t ws_size,
                              hipStream_t stream) {
    (void)n_in; (void)out_size; (void)ws_size;
    const float* x  = (const float*)d_in[0];
    const int* ei   = (const int*)d_in[1];
    const float* W1 = (const float*)d_in[2];
    const float* as1 = (const float*)d_in[3];
    const float* ad1 = (const float*)d_in[4];
    const float* b1  = (const float*)d_in[5];
    const float* W2  = (const float*)d_in[6];
    const float* as2 = (const float*)d_in[7];
    const float* ad2 = (const float*)d_in[8];
    const float* b2  = (const float*)d_in[9];
    const float* W3  = (const float*)d_in[10];
    const float* as3 = (const float*)d_in[11];
    const float* ad3 = (const float*)d_in[12];
    const float* b3  = (const float*)d_in[13];
    const float* p1  = (const float*)d_in[14];
    const float* p2  = (const float*)d_in[15];
    const int N = in_sizes[0] / 256;
    const int E = in_sizes[1] / 2;
    const int NBUK = (N + BN2 - 1) >> BN2SH;
    const int nbp = (E + CHK - 1) / CHK;
    const int nsc = NBUK * nbp;

    char* ws = (char*)d_ws;
    size_t o = 0;
    auto alloc = [&](size_t bytes) { void* p = ws + o; o = (o + bytes + 255) & ~(size_t)255; return p; };
    int* off     = (int*)alloc((size_t)(N + 1) * 4);
    int* bsum    = (int*)alloc(4096);
    int* hist    = (int*)alloc((size_t)nsc * 4);
    int* scanned = (int*)alloc((size_t)nsc * 4);
    int* srt     = (int*)alloc((size_t)E * 4);
    int* stage   = (int*)alloc((size_t)E * 4);
    u16* xb      = (u16*)alloc((size_t)N * 256 * 2);
    u16* g       = (u16*)alloc((size_t)N * 128 * 2);
    float* a_src = (float*)alloc((size_t)N * 8 * 4);
    float* a_dst = (float*)alloc((size_t)N * 8 * 4);
    u16* h1      = (u16*)alloc((size_t)N * 64 * 2);
    u16* h2      = (u16*)alloc((size_t)N * 64 * 2);

    int n4 = N * 256 / 4;
    k_cvt<<<(n4 + 255) / 256, 256, 0, stream>>>(x, xb, n4);

    // CSR build (atomic-free)
    k_hist<<<nbp, 256, 0, stream>>>(ei + E, hist, NBUK, nbp, E);
    int nS = (nsc + 1023) / 1024;
    k_scanpart<<<nS, 1024, 0, stream>>>(hist, bsum, nsc);
    k_scanbsum<<<1, 64, 0, stream>>>(bsum, nS);
    k_scanonly<<<nS, 1024, 0, stream>>>(hist, bsum, scanned, nsc);
    k_part<<<nbp, 256, 0, stream>>>(ei, ei + E, scanned, stage, NBUK, nbp, E);
    k_csr<<<NBUK, 256, 0, stream>>>(stage, scanned, off, srt, NBUK, nbp, N, E);

    int nb64 = (N + 63) / 64;
    int nb4 = (N + 3) / 4;
    int nb8 = (N + 7) / 8;

    // layer 1: x[N,256] @ W1[256,64]
    gemm_k<<<dim3(nb64, 1), 256, 0, stream>>>(xb, 256, (const u16*)nullptr, 0, W1, 64, g, N);
    acomp8<<<nb4, 256, 0, stream>>>(g, as1, ad1, a_src, a_dst, N);
    agg12<<<nb8, 256, 0, stream>>>(g, a_src, a_dst, off, srt, b1, p1, h1, N);

    // layer 2: concat(x, h1)[N,320] @ W2[320,64]
    gemm_k<<<dim3(nb64, 1), 256, 0, stream>>>(xb, 256, h1, 64, W2, 64, g, N);
    acomp8<<<nb4, 256, 0, stream>>>(g, as2, ad2, a_src, a_dst, N);
    agg12<<<nb8, 256, 0, stream>>>(g, a_src, a_dst, off, srt, b2, p2, h2, N);

    // layer 3: h2[N,64] @ W3[64,128], mean over heads + log_softmax
    gemm_k<<<dim3(nb64, 2), 256, 0, stream>>>(h2, 64, (const u16*)nullptr, 0, W3, 128, g, N);
    acomp16<<<nb4, 256, 0, stream>>>(g, as3, ad3, a_src, a_dst, N);
    agg3<<<nb4, 256, 0, stream>>>(g, a_src, a_dst, off, srt, b3, (float*)d_out, N);
}

// Round 7
// 577.043 us; speedup vs baseline: 1.0133x; 1.0003x over previous
//
#include <hip/hip_runtime.h>
#include <hip/hip_bf16.h>
#include <stdint.h>

typedef unsigned short u16;
typedef __attribute__((ext_vector_type(8))) short short8;
typedef __attribute__((ext_vector_type(8))) __bf16 bf16x8;
typedef __attribute__((ext_vector_type(4))) float f32x4;
typedef __attribute__((ext_vector_type(4))) float fv4;

#define DEV static __device__ __forceinline__

DEV float bf2f(u16 u) { uint32_t i = ((uint32_t)u) << 16; float f; __builtin_memcpy(&f, &i, 4); return f; }
DEV u16 f2bf(float f) {
    uint32_t i; __builtin_memcpy(&i, &f, 4);
    uint32_t r = i + 0x7FFFu + ((i >> 16) & 1u);
    return (u16)(r >> 16);
}
DEV float lo16f(uint32_t u) { uint32_t i = u << 16; float f; __builtin_memcpy(&f, &i, 4); return f; }
DEV float hi16f(uint32_t u) { uint32_t i = u & 0xFFFF0000u; float f; __builtin_memcpy(&f, &i, 4); return f; }
DEV uint32_t pack2(float a, float b) { return (uint32_t)f2bf(a) | ((uint32_t)f2bf(b) << 16); }
DEV float lrelu(float x) { return x >= 0.f ? x : 0.2f * x; }

#define CHK 4096      // edges per partition block
#define BN2SH 10      // 1024 nodes per bucket
#define BN2 1024

// ---------------- x -> bf16 pre-convert (streaming, near-roofline) ----------------
__global__ __launch_bounds__(256) void k_cvt(const float* __restrict__ in, u16* __restrict__ out, int n4) {
    int i = blockIdx.x * 256 + threadIdx.x;
    if (i < n4) {
        fv4 v = __builtin_nontemporal_load((const fv4*)in + i);
        uint64_t o = (uint64_t)f2bf(v.x) | ((uint64_t)f2bf(v.y) << 16)
                   | ((uint64_t)f2bf(v.z) << 32) | ((uint64_t)f2bf(v.w) << 48);
        __builtin_nontemporal_store(o, (uint64_t*)out + i);
    }
}

// ---------------- CSR build: atomic-free bucket partition ----------------
__global__ __launch_bounds__(256) void k_hist(const int* __restrict__ dst, int* __restrict__ hist,
                                              int NBUK, int nbp, int E) {
    __shared__ int h[BN2];
    int tid = threadIdx.x;
    for (int i = tid; i < NBUK; i += 256) h[i] = 0;
    __syncthreads();
    int b0 = blockIdx.x * CHK;
    int jend = b0 + CHK < E ? b0 + CHK : E;
    for (int j = b0 + tid; j < jend; j += 256)
        atomicAdd(&h[dst[j] >> BN2SH], 1);
    __syncthreads();
    for (int i = tid; i < NBUK; i += 256) hist[i * nbp + blockIdx.x] = h[i];
}

__global__ void k_scanpart(const int* __restrict__ deg, int* __restrict__ bsum, int n) {
    __shared__ int buf[1024];
    int tid = threadIdx.x;
    int i = blockIdx.x * 1024 + tid;
    int v = (i < n) ? deg[i] : 0;
    buf[tid] = v; __syncthreads();
    for (int d = 512; d > 0; d >>= 1) {
        if (tid < d) buf[tid] += buf[tid + d];
        __syncthreads();
    }
    if (tid == 0) bsum[blockIdx.x] = buf[0];
}

__global__ void k_scanbsum(int* bsum, int nb) {
    if (threadIdx.x == 0) {
        int run = 0;
        for (int b = 0; b < nb; ++b) { int t = bsum[b]; bsum[b] = run; run += t; }
    }
}

__global__ void k_scanonly(const int* __restrict__ in, const int* __restrict__ bsum,
                           int* __restrict__ out, int n) {
    __shared__ int buf[1024];
    int tid = threadIdx.x;
    int i = blockIdx.x * 1024 + tid;
    int v = (i < n) ? in[i] : 0;
    buf[tid] = v; __syncthreads();
    for (int d = 1; d < 1024; d <<= 1) {
        int t = (tid >= d) ? buf[tid - d] : 0;
        __syncthreads();
        buf[tid] += t;
        __syncthreads();
    }
    if (i < n) out[i] = buf[tid] - v + bsum[blockIdx.x];
}

// pass 3: partition edges into bucket-contiguous staging via LDS cursors
// stage entry packed: src (17 bits) | local_dst (10 bits) << 17   [N=100000 < 2^17]
__global__ __launch_bounds__(256) void k_part(const int* __restrict__ src, const int* __restrict__ dst,
                                              const int* __restrict__ scanned, int* __restrict__ stage,
                                              int NBUK, int nbp, int E) {
    __shared__ int cur[BN2];
    int tid = threadIdx.x;
    for (int i = tid; i < NBUK; i += 256) cur[i] = scanned[i * nbp + blockIdx.x];
    __syncthreads();
    int b0 = blockIdx.x * CHK;
    int jend = b0 + CHK < E ? b0 + CHK : E;
    for (int j = b0 + tid; j < jend; j += 256) {
        int d = dst[j];
        int p = atomicAdd(&cur[d >> BN2SH], 1);
        stage[p] = src[j] | ((d & (BN2 - 1)) << 17);
    }
}

// level 2: exact CSR within each bucket (LDS-only atomics, coalesced/local writes)
__global__ __launch_bounds__(256) void k_csr(const int* __restrict__ stage, const int* __restrict__ scanned,
                                             int* __restrict__ off, int* __restrict__ srt,
                                             int NBUK, int nbp, int N, int E) {
    __shared__ int deg[BN2];
    __shared__ int ex[BN2];
    __shared__ int tsum[256];
    int tid = threadIdx.x, b = blockIdx.x;
    int base = b << BN2SH;
    int s0 = scanned[b * nbp];
    int s1 = (b + 1 < NBUK) ? scanned[(b + 1) * nbp] : E;
    for (int i = tid; i < BN2; i += 256) deg[i] = 0;
    __syncthreads();
    for (int j = s0 + tid; j < s1; j += 256) atomicAdd(&deg[(uint32_t)stage[j] >> 17], 1);
    __syncthreads();
    int t4 = tid * 4;
    int d0 = deg[t4], d1 = deg[t4 + 1], d2 = deg[t4 + 2], d3 = deg[t4 + 3];
    int tot = d0 + d1 + d2 + d3;
    tsum[tid] = tot; __syncthreads();
    for (int d = 1; d < 256; d <<= 1) {
        int t = (tid >= d) ? tsum[tid - d] : 0;
        __syncthreads();
        tsum[tid] += t;
        __syncthreads();
    }
    int ebase = tsum[tid] - tot;
    ex[t4] = ebase; ex[t4 + 1] = ebase + d0; ex[t4 + 2] = ebase + d0 + d1; ex[t4 + 3] = ebase + d0 + d1 + d2;
    __syncthreads();
    for (int i = tid; i < BN2; i += 256) { int n = base + i; if (n < N) off[n] = s0 + ex[i]; }
    if (b == 0 && tid == 0) off[N] = E;
    __syncthreads();
    for (int j = s0 + tid; j < s1; j += 256) {
        int sd = stage[j];
        int p = atomicAdd(&ex[(uint32_t)sd >> 17], 1);
        srt[s0 + p] = sd & 0x1FFFF;
    }
}

// ---------------- GEMM: out[N,M](bf16) = concat(A1[N,K1],A2[N,K2])(bf16) @ W[K,M](f32) ----------------
// Fused attention-coefficient epilogue: a_src/a_dst[n,head] = sum_c out[n, head*C+c] * att[head,c]
// computed from the f32 accumulators (att arrays flattened so att[col] with col = head*C + c).
// hs = log2(C): 3 for layers 1/2 (C=8), 4 for layer 3 (C=16). Heads never span column blocks.
__global__ __launch_bounds__(256) void gemm_k(const u16* __restrict__ A1, int K1,
                                              const u16* __restrict__ A2, int K2,
                                              const float* __restrict__ W, int M,
                                              u16* __restrict__ out, int N,
                                              const float* __restrict__ ats, const float* __restrict__ atd,
                                              float* __restrict__ a_src, float* __restrict__ a_dst, int hs) {
    __shared__ u16 wt[64][328];
    __shared__ u16 As[64][40];
    const int K = K1 + K2;
    const int tid = threadIdx.x;
    const int n0 = blockIdx.x * 64;
    const int cb = blockIdx.y * 64;

    for (int idx = tid; idx < K * 64; idx += 256) {
        int k = idx >> 6, m = idx & 63;
        wt[m][k] = f2bf(W[(size_t)k * M + cb + m]);
    }

    const int wv = tid >> 6, lane = tid & 63;
    const int quad = lane >> 4, r = lane & 15;
    f32x4 acc[4];
#pragma unroll
    for (int ct = 0; ct < 4; ++ct) acc[ct] = (f32x4){0.f, 0.f, 0.f, 0.f};

    const int row = tid >> 2, seg = tid & 3;
    const int gl = n0 + row;

    for (int k0 = 0; k0 < K; k0 += 32) {
        int4 v = {0, 0, 0, 0};
        if (gl < N) {
            const u16* base = (k0 < K1) ? (A1 + (size_t)gl * K1 + k0)
                                        : (A2 + (size_t)gl * K2 + (k0 - K1));
            v = *(const int4*)(base + seg * 8);
        }
        *(int4*)&As[row][seg * 8] = v;
        __syncthreads();
        bf16x8 a = __builtin_bit_cast(bf16x8, *(const short8*)&As[wv * 16 + r][quad * 8]);
#pragma unroll
        for (int ct = 0; ct < 4; ++ct) {
            bf16x8 b = __builtin_bit_cast(bf16x8, *(const short8*)&wt[ct * 16 + r][k0 + quad * 8]);
            acc[ct] = __builtin_amdgcn_mfma_f32_16x16x32_bf16(a, b, acc[ct], 0, 0, 0);
        }
        __syncthreads();
    }

    const int rmask = (1 << hs) - 1;       // 7 or 15: lanes sharing one head
#pragma unroll
    for (int ct = 0; ct < 4; ++ct)
#pragma unroll
        for (int rg = 0; rg < 4; ++rg) {
            int grow = n0 + wv * 16 + quad * 4 + rg;
            float p = acc[ct][rg];
            if (grow < N) out[(size_t)grow * M + cb + ct * 16 + r] = f2bf(p);
            // fused a_src/a_dst reduction (same-row lanes share grow; xor stays in quad)
            int col = cb + ct * 16 + r;
            float ps = p * ats[col];
            float pd = p * atd[col];
            ps += __shfl_xor(ps, 1); pd += __shfl_xor(pd, 1);
            ps += __shfl_xor(ps, 2); pd += __shfl_xor(pd, 2);
            ps += __shfl_xor(ps, 4); pd += __shfl_xor(pd, 4);
            if (rmask == 15) { ps += __shfl_xor(ps, 8); pd += __shfl_xor(pd, 8); }
            if ((r & rmask) == 0 && grow < N) {
                int head = col >> hs;
                a_src[grow * 8 + head] = ps;
                a_dst[grow * 8 + head] = pd;
            }
        }
}

// ---------------- layer 1/2 aggregation: 2 nodes/wave, 4 channels/lane (dwordx2 gather) ----------------
__global__ __launch_bounds__(256) void agg12(const u16* __restrict__ g,
                                             const float* __restrict__ a_src, const float* __restrict__ a_dst,
                                             const int* __restrict__ off, const int* __restrict__ srt,
                                             const float* __restrict__ bias, const float* __restrict__ pslope,
                                             u16* __restrict__ hout, int N) {
    int tid = threadIdx.x;
    int lane32 = tid & 31;
    int node = blockIdx.x * 8 + (tid >> 5);
    int nd = node < N ? node : N - 1;
    int lane16 = lane32 & 15;     // channel group: ch [lane16*4, +4)
    int sub    = lane32 >> 4;     // edge sub-slot (0..1)
    int hg     = lane16 >> 1;     // head of gather channels (8 ch/head)
    int hw     = lane32 & 7;      // head for weight layout
    int e4     = lane32 >> 3;     // edge slot for weight layout (0..3)
    const char* gb = (const char*)g;

    float ad_acc = a_dst[nd * 8 + hg];
    float ad_w   = a_dst[nd * 8 + hw];
    float ws = __expf(lrelu(a_src[nd * 8 + hg] + ad_acc));
    float m0 = (sub == 0) ? ws : 0.f;        // self-loop counted once
    uint2 gs = *(const uint2*)(gb + ((size_t)nd << 7) + lane16 * 8);
    float s = m0;
    float acc0 = m0 * lo16f(gs.x), acc1 = m0 * hi16f(gs.x);
    float acc2 = m0 * lo16f(gs.y), acc3 = m0 * hi16f(gs.y);

    int jb = off[nd], je = off[nd + 1];
    int addrH = (tid & 32) * 4;               // byte addr of half-wave base lane
    int addrS = addrH + sub * 32;             // srcv bpermute base
    int addrW = addrS + hg * 4;               // weight bpermute base
    int laneoff = lane16 * 8;                 // byte offset within 128B row

    int idx = 0; float asv = 0.f;
    if (jb < je) {
        int jc = jb + e4; jc = jc < je ? jc : je - 1;
        idx = srt[jc];
        asv = a_src[idx * 8 + hw];
    }
    for (int j = jb; j < je; j += 4) {
        float w = __expf(lrelu(asv + ad_w));
        w = (j + e4 < je) ? w : 0.f;          // pre-zero tail weights at source
        int wi = __builtin_bit_cast(int, w);
        int jn = j + 4 + e4; jn = jn < je ? jn : je - 1;
        int idx_n = srt[jn];
        float as_n = a_src[idx_n * 8 + hw];

        int sv0 = __builtin_amdgcn_ds_bpermute(addrS,      idx);
        int wb0 = __builtin_amdgcn_ds_bpermute(addrW,      wi);
        int sv1 = __builtin_amdgcn_ds_bpermute(addrS + 64, idx);
        int wb1 = __builtin_amdgcn_ds_bpermute(addrW + 64, wi);
        uint2 g0 = *(const uint2*)(gb + (((uint32_t)sv0 << 7) + laneoff));
        uint2 g1 = *(const uint2*)(gb + (((uint32_t)sv1 << 7) + laneoff));
        float wv0 = __builtin_bit_cast(float, wb0);
        float wv1 = __builtin_bit_cast(float, wb1);
        s += wv0;
        acc0 += wv0 * lo16f(g0.x); acc1 += wv0 * hi16f(g0.x);
        acc2 += wv0 * lo16f(g0.y); acc3 += wv0 * hi16f(g0.y);
        s += wv1;
        acc0 += wv1 * lo16f(g1.x); acc1 += wv1 * hi16f(g1.x);
        acc2 += wv1 * lo16f(g1.y); acc3 += wv1 * hi16f(g1.y);
        idx = idx_n; asv = as_n;
    }
    // combine the two edge sub-slots (lanes ^16, within each half-wave)
    s    += __shfl_xor(s,    16);
    acc0 += __shfl_xor(acc0, 16); acc1 += __shfl_xor(acc1, 16);
    acc2 += __shfl_xor(acc2, 16); acc3 += __shfl_xor(acc3, 16);
    if (node < N && sub == 0) {
        float r = 1.f / (s + 1e-16f);
        fv4 bv = *(const fv4*)(bias + lane16 * 4);
        float p = pslope[0];
        float v0 = acc0 * r + bv.x; v0 = v0 >= 0.f ? v0 : p * v0;
        float v1 = acc1 * r + bv.y; v1 = v1 >= 0.f ? v1 : p * v1;
        float v2 = acc2 * r + bv.z; v2 = v2 >= 0.f ? v2 : p * v2;
        float v3 = acc3 * r + bv.w; v3 = v3 >= 0.f ? v3 : p * v3;
        uint2 o; o.x = pack2(v0, v1); o.y = pack2(v2, v3);
        *(uint2*)((char*)hout + ((size_t)node << 7) + lane16 * 8) = o;
    }
}

// ---------------- layer 3 aggregation + head-mean + bias + log_softmax ----------------
__global__ __launch_bounds__(256) void agg3(const u16* __restrict__ g,
                                            const float* __restrict__ a_src, const float* __restrict__ a_dst,
                                            const int* __restrict__ off, const int* __restrict__ srt,
                                            const float* __restrict__ b3, float* __restrict__ out, int N) {
    int tid = threadIdx.x;
    int lane = tid & 63;
    int node = blockIdx.x * 4 + (tid >> 6);
    int nd = node < N ? node : N - 1;
    int lane32 = lane & 31;       // ch group: ch [lane32*4, +4)
    int sub = lane >> 5;          // edge sub-slot (0..1)
    int hg = lane32 >> 2;         // head of gather channels (16 ch/head)
    int hw = lane & 7;            // head for weight layout
    int e8 = lane >> 3;           // edge slot for weight layout (0..7)
    const char* gb = (const char*)g;

    float ad_acc = a_dst[nd * 8 + hg];
    float ad_w   = a_dst[nd * 8 + hw];
    float ws = __expf(lrelu(a_src[nd * 8 + hg] + ad_acc));
    float m0 = (sub == 0) ? ws : 0.f;
    uint2 gs = *(const uint2*)(gb + ((size_t)nd << 8) + lane32 * 8);
    float s = m0;
    float acc0 = m0 * lo16f(gs.x), acc1 = m0 * hi16f(gs.x);
    float acc2 = m0 * lo16f(gs.y), acc3 = m0 * hi16f(gs.y);

    int jb = off[nd], je = off[nd + 1];
    int addrS = sub * 32;                 // srcv bpermute base (t adds +64)
    int addrW = addrS + hg * 4;           // weight bpermute base
    int laneoff = lane32 * 8;             // byte offset within 256B row

    int idx = 0; float asv = 0.f;
    if (jb < je) {
        int jc = jb + e8; jc = jc < je ? jc : je - 1;
        idx = srt[jc];
        asv = a_src[idx * 8 + hw];
    }
    for (int j = jb; j < je; j += 8) {
        float w = __expf(lrelu(asv + ad_w));
        w = (j + e8 < je) ? w : 0.f;      // pre-zero tail weights
        int wi = __builtin_bit_cast(int, w);
        int jn = j + 8 + e8; jn = jn < je ? jn : je - 1;
        int idx_n = srt[jn];
        float as_n = a_src[idx_n * 8 + hw];
#pragma unroll
        for (int t = 0; t < 4; ++t) {
            int sv = __builtin_amdgcn_ds_bpermute(addrS + t * 64, idx);
            int wb = __builtin_amdgcn_ds_bpermute(addrW + t * 64, wi);
            uint2 gv = *(const uint2*)(gb + (((uint32_t)sv << 8) + laneoff));
            float wf = __builtin_bit_cast(float, wb);
            s += wf;
            acc0 += wf * lo16f(gv.x); acc1 += wf * hi16f(gv.x);
            acc2 += wf * lo16f(gv.y); acc3 += wf * hi16f(gv.y);
        }
        idx = idx_n; asv = as_n;
    }
    // combine edge sub-slots (lanes ^32)
    s    += __shfl_xor(s,    32);
    acc0 += __shfl_xor(acc0, 32); acc1 += __shfl_xor(acc1, 32);
    acc2 += __shfl_xor(acc2, 32); acc3 += __shfl_xor(acc3, 32);
    // per-head normalize
    float r = 1.f / (s + 1e-16f);
    acc0 *= r; acc1 *= r; acc2 *= r; acc3 *= r;
    // mean over heads: sum lanes stride-4 (xor 4,8,16)
#pragma unroll
    for (int d = 4; d <= 16; d <<= 1) {
        acc0 += __shfl_xor(acc0, d); acc1 += __shfl_xor(acc1, d);
        acc2 += __shfl_xor(acc2, d); acc3 += __shfl_xor(acc3, d);
    }
    // each lane now holds out-ch [(lane32&3)*4, +4) of the 16 outputs
    fv4 bv = *(const fv4*)(b3 + (lane32 & 3) * 4);
    float v0 = acc0 * 0.125f + bv.x;
    float v1 = acc1 * 0.125f + bv.y;
    float v2 = acc2 * 0.125f + bv.z;
    float v3 = acc3 * 0.125f + bv.w;
    float m = fmaxf(fmaxf(v0, v1), fmaxf(v2, v3));
    m = fmaxf(m, __shfl_xor(m, 1)); m = fmaxf(m, __shfl_xor(m, 2));
    float se = __expf(v0 - m) + __expf(v1 - m) + __expf(v2 - m) + __expf(v3 - m);
    se += __shfl_xor(se, 1); se += __shfl_xor(se, 2);
    float lg = __logf(se);
    if (node < N && lane < 4) {
        float4 o;
        o.x = v0 - m - lg; o.y = v1 - m - lg; o.z = v2 - m - lg; o.w = v3 - m - lg;
        *(float4*)(out + (size_t)node * 16 + lane * 4) = o;
    }
}

// ---------------- launch ----------------
extern "C" void kernel_launch(void* const* d_in, const int* in_sizes, int n_in,
                              void* d_out, int out_size, void* d_ws, size_t ws_size,
                              hipStream_t stream) {
    (void)n_in; (void)out_size; (void)ws_size;
    const float* x  = (const float*)d_in[0];
    const int* ei   = (const int*)d_in[1];
    const float* W1 = (const float*)d_in[2];
    const float* as1 = (const float*)d_in[3];
    const float* ad1 = (const float*)d_in[4];
    const float* b1  = (const float*)d_in[5];
    const float* W2  = (const float*)d_in[6];
    const float* as2 = (const float*)d_in[7];
    const float* ad2 = (const float*)d_in[8];
    const float* b2  = (const float*)d_in[9];
    const float* W3  = (const float*)d_in[10];
    const float* as3 = (const float*)d_in[11];
    const float* ad3 = (const float*)d_in[12];
    const float* b3  = (const float*)d_in[13];
    const float* p1  = (const float*)d_in[14];
    const float* p2  = (const float*)d_in[15];
    const int N = in_sizes[0] / 256;
    const int E = in_sizes[1] / 2;
    const int NBUK = (N + BN2 - 1) >> BN2SH;
    const int nbp = (E + CHK - 1) / CHK;
    const int nsc = NBUK * nbp;

    char* ws = (char*)d_ws;
    size_t o = 0;
    auto alloc = [&](size_t bytes) { void* p = ws + o; o = (o + bytes + 255) & ~(size_t)255; return p; };
    int* off     = (int*)alloc((size_t)(N + 1) * 4);
    int* bsum    = (int*)alloc(4096);
    int* hist    = (int*)alloc((size_t)nsc * 4);
    int* scanned = (int*)alloc((size_t)nsc * 4);
    int* srt     = (int*)alloc((size_t)E * 4);
    int* stage   = (int*)alloc((size_t)E * 4);
    u16* xb      = (u16*)alloc((size_t)N * 256 * 2);
    u16* g       = (u16*)alloc((size_t)N * 128 * 2);
    float* a_src = (float*)alloc((size_t)N * 8 * 4);
    float* a_dst = (float*)alloc((size_t)N * 8 * 4);
    u16* h1      = (u16*)alloc((size_t)N * 64 * 2);
    u16* h2      = (u16*)alloc((size_t)N * 64 * 2);

    int n4 = N * 256 / 4;
    k_cvt<<<(n4 + 255) / 256, 256, 0, stream>>>(x, xb, n4);

    // CSR build (atomic-free)
    k_hist<<<nbp, 256, 0, stream>>>(ei + E, hist, NBUK, nbp, E);
    int nS = (nsc + 1023) / 1024;
    k_scanpart<<<nS, 1024, 0, stream>>>(hist, bsum, nsc);
    k_scanbsum<<<1, 64, 0, stream>>>(bsum, nS);
    k_scanonly<<<nS, 1024, 0, stream>>>(hist, bsum, scanned, nsc);
    k_part<<<nbp, 256, 0, stream>>>(ei, ei + E, scanned, stage, NBUK, nbp, E);
    k_csr<<<NBUK, 256, 0, stream>>>(stage, scanned, off, srt, NBUK, nbp, N, E);

    int nb64 = (N + 63) / 64;
    int nb4 = (N + 3) / 4;
    int nb8 = (N + 7) / 8;

    // layer 1: x[N,256] @ W1[256,64]  (+ fused acomp, C=8 -> hs=3)
    gemm_k<<<dim3(nb64, 1), 256, 0, stream>>>(xb, 256, (const u16*)nullptr, 0, W1, 64, g, N,
                                              as1, ad1, a_src, a_dst, 3);
    agg12<<<nb8, 256, 0, stream>>>(g, a_src, a_dst, off, srt, b1, p1, h1, N);

    // layer 2: concat(x, h1)[N,320] @ W2[320,64]  (+ fused acomp, hs=3)
    gemm_k<<<dim3(nb64, 1), 256, 0, stream>>>(xb, 256, h1, 64, W2, 64, g, N,
                                              as2, ad2, a_src, a_dst, 3);
    agg12<<<nb8, 256, 0, stream>>>(g, a_src, a_dst, off, srt, b2, p2, h2, N);

    // layer 3: h2[N,64] @ W3[64,128]  (+ fused acomp, C=16 -> hs=4), mean + log_softmax
    gemm_k<<<dim3(nb64, 2), 256, 0, stream>>>(h2, 64, (const u16*)nullptr, 0, W3, 128, g, N,
                                              as3, ad3, a_src, a_dst, 4);
    agg3<<<nb4, 256, 0, stream>>>(g, a_src, a_dst, off, srt, b3, (float*)d_out, N);
}

// Round 8
// 534.349 us; speedup vs baseline: 1.0942x; 1.0799x over previous
//
#include <hip/hip_runtime.h>
#include <hip/hip_bf16.h>
#include <stdint.h>

typedef unsigned short u16;
typedef __attribute__((ext_vector_type(8))) short short8;
typedef __attribute__((ext_vector_type(8))) __bf16 bf16x8;
typedef __attribute__((ext_vector_type(4))) float f32x4;
typedef __attribute__((ext_vector_type(4))) float fv4;

#define DEV static __device__ __forceinline__

DEV float bf2f(u16 u) { uint32_t i = ((uint32_t)u) << 16; float f; __builtin_memcpy(&f, &i, 4); return f; }
DEV u16 f2bf(float f) {
    uint32_t i; __builtin_memcpy(&i, &f, 4);
    uint32_t r = i + 0x7FFFu + ((i >> 16) & 1u);
    return (u16)(r >> 16);
}
DEV float lo16f(uint32_t u) { uint32_t i = u << 16; float f; __builtin_memcpy(&f, &i, 4); return f; }
DEV float hi16f(uint32_t u) { uint32_t i = u & 0xFFFF0000u; float f; __builtin_memcpy(&f, &i, 4); return f; }
DEV uint32_t pack2(float a, float b) { return (uint32_t)f2bf(a) | ((uint32_t)f2bf(b) << 16); }
DEV float lrelu(float x) { return x >= 0.f ? x : 0.2f * x; }

#define CHK 4096      // edges per partition block
#define BN2SH 10      // 1024 nodes per bucket
#define BN2 1024

// ---------------- x -> bf16 pre-convert (streaming, near-roofline) ----------------
__global__ __launch_bounds__(256) void k_cvt(const float* __restrict__ in, u16* __restrict__ out, int n4) {
    int i = blockIdx.x * 256 + threadIdx.x;
    if (i < n4) {
        fv4 v = __builtin_nontemporal_load((const fv4*)in + i);
        uint64_t o = (uint64_t)f2bf(v.x) | ((uint64_t)f2bf(v.y) << 16)
                   | ((uint64_t)f2bf(v.z) << 32) | ((uint64_t)f2bf(v.w) << 48);
        __builtin_nontemporal_store(o, (uint64_t*)out + i);
    }
}

// ---------------- CSR build: atomic-free bucket partition ----------------
__global__ __launch_bounds__(256) void k_hist(const int* __restrict__ dst, int* __restrict__ hist,
                                              int NBUK, int nbp, int E) {
    __shared__ int h[BN2];
    int tid = threadIdx.x;
    for (int i = tid; i < NBUK; i += 256) h[i] = 0;
    __syncthreads();
    int b0 = blockIdx.x * CHK;
    int jend = b0 + CHK < E ? b0 + CHK : E;
    for (int j = b0 + tid; j < jend; j += 256)
        atomicAdd(&h[dst[j] >> BN2SH], 1);
    __syncthreads();
    for (int i = tid; i < NBUK; i += 256) hist[i * nbp + blockIdx.x] = h[i];
}

__global__ void k_scanpart(const int* __restrict__ deg, int* __restrict__ bsum, int n) {
    __shared__ int buf[1024];
    int tid = threadIdx.x;
    int i = blockIdx.x * 1024 + tid;
    int v = (i < n) ? deg[i] : 0;
    buf[tid] = v; __syncthreads();
    for (int d = 512; d > 0; d >>= 1) {
        if (tid < d) buf[tid] += buf[tid + d];
        __syncthreads();
    }
    if (tid == 0) bsum[blockIdx.x] = buf[0];
}

__global__ void k_scanbsum(int* bsum, int nb) {
    if (threadIdx.x == 0) {
        int run = 0;
        for (int b = 0; b < nb; ++b) { int t = bsum[b]; bsum[b] = run; run += t; }
    }
}

__global__ void k_scanonly(const int* __restrict__ in, const int* __restrict__ bsum,
                           int* __restrict__ out, int n) {
    __shared__ int buf[1024];
    int tid = threadIdx.x;
    int i = blockIdx.x * 1024 + tid;
    int v = (i < n) ? in[i] : 0;
    buf[tid] = v; __syncthreads();
    for (int d = 1; d < 1024; d <<= 1) {
        int t = (tid >= d) ? buf[tid - d] : 0;
        __syncthreads();
        buf[tid] += t;
        __syncthreads();
    }
    if (i < n) out[i] = buf[tid] - v + bsum[blockIdx.x];
}

// pass 3: partition edges into bucket-contiguous staging via LDS cursors
// stage entry packed: src (17 bits) | local_dst (10 bits) << 17   [N=100000 < 2^17]
__global__ __launch_bounds__(256) void k_part(const int* __restrict__ src, const int* __restrict__ dst,
                                              const int* __restrict__ scanned, int* __restrict__ stage,
                                              int NBUK, int nbp, int E) {
    __shared__ int cur[BN2];
    int tid = threadIdx.x;
    for (int i = tid; i < NBUK; i += 256) cur[i] = scanned[i * nbp + blockIdx.x];
    __syncthreads();
    int b0 = blockIdx.x * CHK;
    int jend = b0 + CHK < E ? b0 + CHK : E;
    for (int j = b0 + tid; j < jend; j += 256) {
        int d = dst[j];
        int p = atomicAdd(&cur[d >> BN2SH], 1);
        stage[p] = src[j] | ((d & (BN2 - 1)) << 17);
    }
}

// level 2: exact CSR within each bucket (LDS-only atomics, coalesced/local writes)
__global__ __launch_bounds__(256) void k_csr(const int* __restrict__ stage, const int* __restrict__ scanned,
                                             int* __restrict__ off, int* __restrict__ srt,
                                             int NBUK, int nbp, int N, int E) {
    __shared__ int deg[BN2];
    __shared__ int ex[BN2];
    __shared__ int tsum[256];
    int tid = threadIdx.x, b = blockIdx.x;
    int base = b << BN2SH;
    int s0 = scanned[b * nbp];
    int s1 = (b + 1 < NBUK) ? scanned[(b + 1) * nbp] : E;
    for (int i = tid; i < BN2; i += 256) deg[i] = 0;
    __syncthreads();
    for (int j = s0 + tid; j < s1; j += 256) atomicAdd(&deg[(uint32_t)stage[j] >> 17], 1);
    __syncthreads();
    int t4 = tid * 4;
    int d0 = deg[t4], d1 = deg[t4 + 1], d2 = deg[t4 + 2], d3 = deg[t4 + 3];
    int tot = d0 + d1 + d2 + d3;
    tsum[tid] = tot; __syncthreads();
    for (int d = 1; d < 256; d <<= 1) {
        int t = (tid >= d) ? tsum[tid - d] : 0;
        __syncthreads();
        tsum[tid] += t;
        __syncthreads();
    }
    int ebase = tsum[tid] - tot;
    ex[t4] = ebase; ex[t4 + 1] = ebase + d0; ex[t4 + 2] = ebase + d0 + d1; ex[t4 + 3] = ebase + d0 + d1 + d2;
    __syncthreads();
    for (int i = tid; i < BN2; i += 256) { int n = base + i; if (n < N) off[n] = s0 + ex[i]; }
    if (b == 0 && tid == 0) off[N] = E;
    __syncthreads();
    for (int j = s0 + tid; j < s1; j += 256) {
        int sd = stage[j];
        int p = atomicAdd(&ex[(uint32_t)sd >> 17], 1);
        srt[s0 + p] = sd & 0x1FFFF;
    }
}

// ---------------- GEMM: out[N,M](bf16) = concat(A1[N,K1],A2[N,K2])(bf16) @ W[K,M](f32) ----------------
// Barrier-free K-loop: W staged once in chunk-major LDS (wt2[k/8][m][8], 16B units);
// A-fragments loaded per-lane directly from global (16B, line-shared across quads, L1-served).
// Fused attention-coefficient epilogue (a_src/a_dst from f32 accumulators); hs = log2(C).
__global__ __launch_bounds__(256) void gemm_k(const u16* __restrict__ A1, int K1,
                                              const u16* __restrict__ A2, int K2,
                                              const float* __restrict__ W, int M,
                                              u16* __restrict__ out, int N,
                                              const float* __restrict__ ats, const float* __restrict__ atd,
                                              float* __restrict__ a_src, float* __restrict__ a_dst, int hs) {
    __shared__ u16 wt2[40][64][8];          // [k/8][m][k%8], max K=320 -> 40 KB
    const int K = K1 + K2;
    const int nc = K >> 3;
    const int tid = threadIdx.x;
    const int n0 = blockIdx.x * 64;
    const int cb = blockIdx.y * 64;

    for (int p = tid; p < (nc << 6); p += 256) {
        int c = p >> 6, m = p & 63;
        const float* wp = W + ((size_t)(c << 3)) * M + cb + m;
        uint64_t w0 = (uint64_t)f2bf(wp[0])
                    | ((uint64_t)f2bf(wp[(size_t)M]) << 16)
                    | ((uint64_t)f2bf(wp[(size_t)2 * M]) << 32)
                    | ((uint64_t)f2bf(wp[(size_t)3 * M]) << 48);
        uint64_t w1 = (uint64_t)f2bf(wp[(size_t)4 * M])
                    | ((uint64_t)f2bf(wp[(size_t)5 * M]) << 16)
                    | ((uint64_t)f2bf(wp[(size_t)6 * M]) << 32)
                    | ((uint64_t)f2bf(wp[(size_t)7 * M]) << 48);
        uint64_t* d = (uint64_t*)&wt2[c][m][0];
        d[0] = w0; d[1] = w1;
    }
    __syncthreads();

    const int wv = tid >> 6, lane = tid & 63;
    const int quad = lane >> 4, r = lane & 15;
    f32x4 acc[4];
#pragma unroll
    for (int ct = 0; ct < 4; ++ct) acc[ct] = (f32x4){0.f, 0.f, 0.f, 0.f};

    int arow = n0 + wv * 16 + r;
    int ar = arow < N ? arow : N - 1;
    const u16* rowA1 = A1 + (size_t)ar * K1;
    const u16* rowA2 = A2 ? (A2 + (size_t)ar * K2 - K1) : rowA1;

    const int nit = K >> 5;
    for (int it = 0; it < nit; ++it) {
        int kk = (it << 5) + quad * 8;
        const u16* ap = (kk < K1) ? (rowA1 + kk) : (rowA2 + kk);
        bf16x8 a = __builtin_bit_cast(bf16x8, *(const short8*)ap);
        int cbase = it << 2;
#pragma unroll
        for (int ct = 0; ct < 4; ++ct) {
            bf16x8 b = __builtin_bit_cast(bf16x8, *(const short8*)&wt2[cbase + quad][ct * 16 + r][0]);
            acc[ct] = __builtin_amdgcn_mfma_f32_16x16x32_bf16(a, b, acc[ct], 0, 0, 0);
        }
    }

    const int rmask = (1 << hs) - 1;       // 7 or 15: lanes sharing one head
#pragma unroll
    for (int ct = 0; ct < 4; ++ct) {
        int col = cb + ct * 16 + r;
        float as_c = ats[col];
        float ad_c = atd[col];
#pragma unroll
        for (int rg = 0; rg < 4; ++rg) {
            int grow = n0 + wv * 16 + quad * 4 + rg;
            float p = acc[ct][rg];
            if (grow < N) out[(size_t)grow * M + col] = f2bf(p);
            float ps = p * as_c;
            float pd = p * ad_c;
            ps += __shfl_xor(ps, 1); pd += __shfl_xor(pd, 1);
            ps += __shfl_xor(ps, 2); pd += __shfl_xor(pd, 2);
            ps += __shfl_xor(ps, 4); pd += __shfl_xor(pd, 4);
            if (rmask == 15) { ps += __shfl_xor(ps, 8); pd += __shfl_xor(pd, 8); }
            if ((r & rmask) == 0 && grow < N) {
                int head = col >> hs;
                a_src[grow * 8 + head] = ps;
                a_dst[grow * 8 + head] = pd;
            }
        }
    }
}

// ---------------- layer 1/2 aggregation: 2 nodes/wave, 4 channels/lane (dwordx2 gather) ----------------
__global__ __launch_bounds__(256) void agg12(const u16* __restrict__ g,
                                             const float* __restrict__ a_src, const float* __restrict__ a_dst,
                                             const int* __restrict__ off, const int* __restrict__ srt,
                                             const float* __restrict__ bias, const float* __restrict__ pslope,
                                             u16* __restrict__ hout, int N) {
    int tid = threadIdx.x;
    int lane32 = tid & 31;
    int node = blockIdx.x * 8 + (tid >> 5);
    int nd = node < N ? node : N - 1;
    int lane16 = lane32 & 15;     // channel group: ch [lane16*4, +4)
    int sub    = lane32 >> 4;     // edge sub-slot (0..1)
    int hg     = lane16 >> 1;     // head of gather channels (8 ch/head)
    int hw     = lane32 & 7;      // head for weight layout
    int e4     = lane32 >> 3;     // edge slot for weight layout (0..3)
    const char* gb = (const char*)g;

    float ad_acc = a_dst[nd * 8 + hg];
    float ad_w   = a_dst[nd * 8 + hw];
    float ws = __expf(lrelu(a_src[nd * 8 + hg] + ad_acc));
    float m0 = (sub == 0) ? ws : 0.f;        // self-loop counted once
    uint2 gs = *(const uint2*)(gb + ((size_t)nd << 7) + lane16 * 8);
    float s = m0;
    float acc0 = m0 * lo16f(gs.x), acc1 = m0 * hi16f(gs.x);
    float acc2 = m0 * lo16f(gs.y), acc3 = m0 * hi16f(gs.y);

    int jb = off[nd], je = off[nd + 1];
    int addrH = (tid & 32) * 4;               // byte addr of half-wave base lane
    int addrS = addrH + sub * 32;             // srcv bpermute base
    int addrW = addrS + hg * 4;               // weight bpermute base
    int laneoff = lane16 * 8;                 // byte offset within 128B row

    int idx = 0; float asv = 0.f;
    if (jb < je) {
        int jc = jb + e4; jc = jc < je ? jc : je - 1;
        idx = srt[jc];
        asv = a_src[idx * 8 + hw];
    }
    for (int j = jb; j < je; j += 4) {
        float w = __expf(lrelu(asv + ad_w));
        w = (j + e4 < je) ? w : 0.f;          // pre-zero tail weights at source
        int wi = __builtin_bit_cast(int, w);
        int jn = j + 4 + e4; jn = jn < je ? jn : je - 1;
        int idx_n = srt[jn];
        float as_n = a_src[idx_n * 8 + hw];

        int sv0 = __builtin_amdgcn_ds_bpermute(addrS,      idx);
        int wb0 = __builtin_amdgcn_ds_bpermute(addrW,      wi);
        int sv1 = __builtin_amdgcn_ds_bpermute(addrS + 64, idx);
        int wb1 = __builtin_amdgcn_ds_bpermute(addrW + 64, wi);
        uint2 g0 = *(const uint2*)(gb + (((uint32_t)sv0 << 7) + laneoff));
        uint2 g1 = *(const uint2*)(gb + (((uint32_t)sv1 << 7) + laneoff));
        float wv0 = __builtin_bit_cast(float, wb0);
        float wv1 = __builtin_bit_cast(float, wb1);
        s += wv0;
        acc0 += wv0 * lo16f(g0.x); acc1 += wv0 * hi16f(g0.x);
        acc2 += wv0 * lo16f(g0.y); acc3 += wv0 * hi16f(g0.y);
        s += wv1;
        acc0 += wv1 * lo16f(g1.x); acc1 += wv1 * hi16f(g1.x);
        acc2 += wv1 * lo16f(g1.y); acc3 += wv1 * hi16f(g1.y);
        idx = idx_n; asv = as_n;
    }
    // combine the two edge sub-slots (lanes ^16, within each half-wave)
    s    += __shfl_xor(s,    16);
    acc0 += __shfl_xor(acc0, 16); acc1 += __shfl_xor(acc1, 16);
    acc2 += __shfl_xor(acc2, 16); acc3 += __shfl_xor(acc3, 16);
    if (node < N && sub == 0) {
        float r = 1.f / (s + 1e-16f);
        fv4 bv = *(const fv4*)(bias + lane16 * 4);
        float p = pslope[0];
        float v0 = acc0 * r + bv.x; v0 = v0 >= 0.f ? v0 : p * v0;
        float v1 = acc1 * r + bv.y; v1 = v1 >= 0.f ? v1 : p * v1;
        float v2 = acc2 * r + bv.z; v2 = v2 >= 0.f ? v2 : p * v2;
        float v3 = acc3 * r + bv.w; v3 = v3 >= 0.f ? v3 : p * v3;
        uint2 o; o.x = pack2(v0, v1); o.y = pack2(v2, v3);
        *(uint2*)((char*)hout + ((size_t)node << 7) + lane16 * 8) = o;
    }
}

// ---------------- layer 3 aggregation + head-mean + bias + log_softmax ----------------
__global__ __launch_bounds__(256) void agg3(const u16* __restrict__ g,
                                            const float* __restrict__ a_src, const float* __restrict__ a_dst,
                                            const int* __restrict__ off, const int* __restrict__ srt,
                                            const float* __restrict__ b3, float* __restrict__ out, int N) {
    int tid = threadIdx.x;
    int lane = tid & 63;
    int node = blockIdx.x * 4 + (tid >> 6);
    int nd = node < N ? node : N - 1;
    int lane32 = lane & 31;       // ch group: ch [lane32*4, +4)
    int sub = lane >> 5;          // edge sub-slot (0..1)
    int hg = lane32 >> 2;         // head of gather channels (16 ch/head)
    int hw = lane & 7;            // head for weight layout
    int e8 = lane >> 3;           // edge slot for weight layout (0..7)
    const char* gb = (const char*)g;

    float ad_acc = a_dst[nd * 8 + hg];
    float ad_w   = a_dst[nd * 8 + hw];
    float ws = __expf(lrelu(a_src[nd * 8 + hg] + ad_acc));
    float m0 = (sub == 0) ? ws : 0.f;
    uint2 gs = *(const uint2*)(gb + ((size_t)nd << 8) + lane32 * 8);
    float s = m0;
    float acc0 = m0 * lo16f(gs.x), acc1 = m0 * hi16f(gs.x);
    float acc2 = m0 * lo16f(gs.y), acc3 = m0 * hi16f(gs.y);

    int jb = off[nd], je = off[nd + 1];
    int addrS = sub * 32;                 // srcv bpermute base (t adds +64)
    int addrW = addrS + hg * 4;           // weight bpermute base
    int laneoff = lane32 * 8;             // byte offset within 256B row

    int idx = 0; float asv = 0.f;
    if (jb < je) {
        int jc = jb + e8; jc = jc < je ? jc : je - 1;
        idx = srt[jc];
        asv = a_src[idx * 8 + hw];
    }
    for (int j = jb; j < je; j += 8) {
        float w = __expf(lrelu(asv + ad_w));
        w = (j + e8 < je) ? w : 0.f;      // pre-zero tail weights
        int wi = __builtin_bit_cast(int, w);
        int jn = j + 8 + e8; jn = jn < je ? jn : je - 1;
        int idx_n = srt[jn];
        float as_n = a_src[idx_n * 8 + hw];
#pragma unroll
        for (int t = 0; t < 4; ++t) {
            int sv = __builtin_amdgcn_ds_bpermute(addrS + t * 64, idx);
            int wb = __builtin_amdgcn_ds_bpermute(addrW + t * 64, wi);
            uint2 gv = *(const uint2*)(gb + (((uint32_t)sv << 8) + laneoff));
            float wf = __builtin_bit_cast(float, wb);
            s += wf;
            acc0 += wf * lo16f(gv.x); acc1 += wf * hi16f(gv.x);
            acc2 += wf * lo16f(gv.y); acc3 += wf * hi16f(gv.y);
        }
        idx = idx_n; asv = as_n;
    }
    // combine edge sub-slots (lanes ^32)
    s    += __shfl_xor(s,    32);
    acc0 += __shfl_xor(acc0, 32); acc1 += __shfl_xor(acc1, 32);
    acc2 += __shfl_xor(acc2, 32); acc3 += __shfl_xor(acc3, 32);
    // per-head normalize
    float r = 1.f / (s + 1e-16f);
    acc0 *= r; acc1 *= r; acc2 *= r; acc3 *= r;
    // mean over heads: sum lanes stride-4 (xor 4,8,16)
#pragma unroll
    for (int d = 4; d <= 16; d <<= 1) {
        acc0 += __shfl_xor(acc0, d); acc1 += __shfl_xor(acc1, d);
        acc2 += __shfl_xor(acc2, d); acc3 += __shfl_xor(acc3, d);
    }
    // each lane now holds out-ch [(lane32&3)*4, +4) of the 16 outputs
    fv4 bv = *(const fv4*)(b3 + (lane32 & 3) * 4);
    float v0 = acc0 * 0.125f + bv.x;
    float v1 = acc1 * 0.125f + bv.y;
    float v2 = acc2 * 0.125f + bv.z;
    float v3 = acc3 * 0.125f + bv.w;
    float m = fmaxf(fmaxf(v0, v1), fmaxf(v2, v3));
    m = fmaxf(m, __shfl_xor(m, 1)); m = fmaxf(m, __shfl_xor(m, 2));
    float se = __expf(v0 - m) + __expf(v1 - m) + __expf(v2 - m) + __expf(v3 - m);
    se += __shfl_xor(se, 1); se += __shfl_xor(se, 2);
    float lg = __logf(se);
    if (node < N && lane < 4) {
        float4 o;
        o.x = v0 - m - lg; o.y = v1 - m - lg; o.z = v2 - m - lg; o.w = v3 - m - lg;
        *(float4*)(out + (size_t)node * 16 + lane * 4) = o;
    }
}

// ---------------- launch ----------------
extern "C" void kernel_launch(void* const* d_in, const int* in_sizes, int n_in,
                              void* d_out, int out_size, void* d_ws, size_t ws_size,
                              hipStream_t stream) {
    (void)n_in; (void)out_size; (void)ws_size;
    const float* x  = (const float*)d_in[0];
    const int* ei   = (const int*)d_in[1];
    const float* W1 = (const float*)d_in[2];
    const float* as1 = (const float*)d_in[3];
    const float* ad1 = (const float*)d_in[4];
    const float* b1  = (const float*)d_in[5];
    const float* W2  = (const float*)d_in[6];
    const float* as2 = (const float*)d_in[7];
    const float* ad2 = (const float*)d_in[8];
    const float* b2  = (const float*)d_in[9];
    const float* W3  = (const float*)d_in[10];
    const float* as3 = (const float*)d_in[11];
    const float* ad3 = (const float*)d_in[12];
    const float* b3  = (const float*)d_in[13];
    const float* p1  = (const float*)d_in[14];
    const float* p2  = (const float*)d_in[15];
    const int N = in_sizes[0] / 256;
    const int E = in_sizes[1] / 2;
    const int NBUK = (N + BN2 - 1) >> BN2SH;
    const int nbp = (E + CHK - 1) / CHK;
    const int nsc = NBUK * nbp;

    char* ws = (char*)d_ws;
    size_t o = 0;
    auto alloc = [&](size_t bytes) { void* p = ws + o; o = (o + bytes + 255) & ~(size_t)255; return p; };
    int* off     = (int*)alloc((size_t)(N + 1) * 4);
    int* bsum    = (int*)alloc(4096);
    int* hist    = (int*)alloc((size_t)nsc * 4);
    int* scanned = (int*)alloc((size_t)nsc * 4);
    int* srt     = (int*)alloc((size_t)E * 4);
    int* stage   = (int*)alloc((size_t)E * 4);
    u16* xb      = (u16*)alloc((size_t)N * 256 * 2);
    u16* g       = (u16*)alloc((size_t)N * 128 * 2);
    float* a_src = (float*)alloc((size_t)N * 8 * 4);
    float* a_dst = (float*)alloc((size_t)N * 8 * 4);
    u16* h1      = (u16*)alloc((size_t)N * 64 * 2);
    u16* h2      = (u16*)alloc((size_t)N * 64 * 2);

    int n4 = N * 256 / 4;
    k_cvt<<<(n4 + 255) / 256, 256, 0, stream>>>(x, xb, n4);

    // CSR build (atomic-free)
    k_hist<<<nbp, 256, 0, stream>>>(ei + E, hist, NBUK, nbp, E);
    int nS = (nsc + 1023) / 1024;
    k_scanpart<<<nS, 1024, 0, stream>>>(hist, bsum, nsc);
    k_scanbsum<<<1, 64, 0, stream>>>(bsum, nS);
    k_scanonly<<<nS, 1024, 0, stream>>>(hist, bsum, scanned, nsc);
    k_part<<<nbp, 256, 0, stream>>>(ei, ei + E, scanned, stage, NBUK, nbp, E);
    k_csr<<<NBUK, 256, 0, stream>>>(stage, scanned, off, srt, NBUK, nbp, N, E);

    int nb64 = (N + 63) / 64;
    int nb4 = (N + 3) / 4;
    int nb8 = (N + 7) / 8;

    // layer 1: x[N,256] @ W1[256,64]  (+ fused acomp, C=8 -> hs=3)
    gemm_k<<<dim3(nb64, 1), 256, 0, stream>>>(xb, 256, (const u16*)nullptr, 0, W1, 64, g, N,
                                              as1, ad1, a_src, a_dst, 3);
    agg12<<<nb8, 256, 0, stream>>>(g, a_src, a_dst, off, srt, b1, p1, h1, N);

    // layer 2: concat(x, h1)[N,320] @ W2[320,64]  (+ fused acomp, hs=3)
    gemm_k<<<dim3(nb64, 1), 256, 0, stream>>>(xb, 256, h1, 64, W2, 64, g, N,
                                              as2, ad2, a_src, a_dst, 3);
    agg12<<<nb8, 256, 0, stream>>>(g, a_src, a_dst, off, srt, b2, p2, h2, N);

    // layer 3: h2[N,64] @ W3[64,128]  (+ fused acomp, C=16 -> hs=4), mean + log_softmax
    gemm_k<<<dim3(nb64, 2), 256, 0, stream>>>(h2, 64, (const u16*)nullptr, 0, W3, 128, g, N,
                                              as3, ad3, a_src, a_dst, 4);
    agg3<<<nb4, 256, 0, stream>>>(g, a_src, a_dst, off, srt, b3, (float*)d_out, N);
}